// Round 2
// baseline (1388.043 us; speedup 1.0000x reference)
//
#include <hip/hip_runtime.h>
#include <math.h>

#define D_MODEL   1024
#define D_INNER_  2048
#define D_STATE_  16
#define DT_RANK_  64
#define SEQ       1024
#define NTOK      2048          // B * L
#define XPROJ_N   96            // dt_rank + 2*d_state

// ---------------- bf16 storage helpers (fallback path) ---------------------
__device__ __forceinline__ float bf2f(unsigned short u) {
  return __uint_as_float(((unsigned int)u) << 16);
}
__device__ __forceinline__ unsigned short f2bf(float f) {
  unsigned int x = __float_as_uint(f);
  x += 0x7FFF + ((x >> 16) & 1);          // round-to-nearest-even
  return (unsigned short)(x >> 16);
}

template <typename T> struct VIO;
template <> struct VIO<float> {
  static __device__ __forceinline__ float4 ld4(const float* p) { return *(const float4*)p; }
  static __device__ __forceinline__ void st4(float* p, float4 v) { *(float4*)p = v; }
  static __device__ __forceinline__ float ld(const float* p) { return *p; }
  static __device__ __forceinline__ void st(float* p, float v) { *p = v; }
};
template <> struct VIO<unsigned short> {
  static __device__ __forceinline__ float4 ld4(const unsigned short* p) {
    ushort4 u = *(const ushort4*)p;
    return make_float4(bf2f(u.x), bf2f(u.y), bf2f(u.z), bf2f(u.w));
  }
  static __device__ __forceinline__ void st4(unsigned short* p, float4 v) {
    ushort4 u; u.x = f2bf(v.x); u.y = f2bf(v.y); u.z = f2bf(v.z); u.w = f2bf(v.w);
    *(ushort4*)p = u;
  }
  static __device__ __forceinline__ float ld(const unsigned short* p) { return bf2f(*p); }
  static __device__ __forceinline__ void st(unsigned short* p, float v) { *p = f2bf(v); }
};

// ---------------------------------------------------------------------------
// NT GEMM: C[M][N] = A[M][K] * B[N][K]^T.  M,N,K % 64 == 0.  LDS held in fp32;
// storage types only affect global staging loads / epilogue stores.
// ---------------------------------------------------------------------------
template <typename TA, typename TB, typename TC>
__global__ __launch_bounds__(256) void gemm_nt(
    const TA* __restrict__ A, const TB* __restrict__ B,
    TC* __restrict__ C, int M, int N, int K)
{
  __shared__ float As[64][68];
  __shared__ float Bs[64][68];
  const int ntiles = N >> 6;
  const int mt = blockIdx.x / ntiles, nt = blockIdx.x % ntiles;
  const int m0 = mt << 6, n0 = nt << 6;
  const int tid = threadIdx.x;
  const int lr = tid >> 2;              // load row 0..63
  const int lc = (tid & 3) << 4;        // load col start {0,16,32,48}
  const int tr = tid >> 4, tc = tid & 15;
  float acc[4][4] = {{0.f, 0.f, 0.f, 0.f}, {0.f, 0.f, 0.f, 0.f},
                     {0.f, 0.f, 0.f, 0.f}, {0.f, 0.f, 0.f, 0.f}};
  const TA* ag = A + (size_t)(m0 + lr) * K + lc;
  const TB* bg = B + (size_t)(n0 + lr) * K + lc;

  for (int k0 = 0; k0 < K; k0 += 64) {
    float4 a0 = VIO<TA>::ld4(ag + k0);
    float4 a1 = VIO<TA>::ld4(ag + k0 + 4);
    float4 a2 = VIO<TA>::ld4(ag + k0 + 8);
    float4 a3 = VIO<TA>::ld4(ag + k0 + 12);
    float4 b0 = VIO<TB>::ld4(bg + k0);
    float4 b1 = VIO<TB>::ld4(bg + k0 + 4);
    float4 b2 = VIO<TB>::ld4(bg + k0 + 8);
    float4 b3 = VIO<TB>::ld4(bg + k0 + 12);
    __syncthreads();                    // protect LDS reads of previous iter
    *(float4*)&As[lr][lc]      = a0;
    *(float4*)&As[lr][lc + 4]  = a1;
    *(float4*)&As[lr][lc + 8]  = a2;
    *(float4*)&As[lr][lc + 12] = a3;
    *(float4*)&Bs[lr][lc]      = b0;
    *(float4*)&Bs[lr][lc + 4]  = b1;
    *(float4*)&Bs[lr][lc + 8]  = b2;
    *(float4*)&Bs[lr][lc + 12] = b3;
    __syncthreads();
    for (int kk = 0; kk < 64; kk += 4) {
      float4 a[4], b[4];
#pragma unroll
      for (int i = 0; i < 4; ++i) a[i] = *(const float4*)&As[tr * 4 + i][kk];
#pragma unroll
      for (int j = 0; j < 4; ++j) b[j] = *(const float4*)&Bs[tc * 4 + j][kk];
#pragma unroll
      for (int i = 0; i < 4; ++i)
#pragma unroll
        for (int j = 0; j < 4; ++j)
          acc[i][j] += a[i].x * b[j].x + a[i].y * b[j].y +
                       a[i].z * b[j].z + a[i].w * b[j].w;
    }
  }
#pragma unroll
  for (int i = 0; i < 4; ++i) {
    float4 v = make_float4(acc[i][0], acc[i][1], acc[i][2], acc[i][3]);
    VIO<TC>::st4(C + (size_t)(m0 + tr * 4 + i) * N + n0 + tc * 4, v);
  }
}

// ---------------------------------------------------------------------------
// Causal depthwise conv (k=4, left pad 3) + bias + silu.  One thread per
// (token, channel).  xc is a contiguous (NTOK, D_INNER) buffer now.
// ---------------------------------------------------------------------------
template <typename T>
__global__ __launch_bounds__(256) void conv_silu(
    const T* __restrict__ xc, const float* __restrict__ Wc,
    const float* __restrict__ bc, T* __restrict__ xs)
{
  const int idx = blockIdx.x * 256 + threadIdx.x;   // NTOK * D_INNER
  const int d = idx & (D_INNER_ - 1);
  const int t = idx >> 11;                          // token = b*L + l
  const int l = t & (SEQ - 1);
  const float4 w = *(const float4*)(Wc + d * 4);    // W_conv[d][0][0..3]
  const T* col = xc + (size_t)t * D_INNER_ + d;
  float acc = bc[d] + VIO<T>::ld(col) * w.w;
  if (l >= 1) acc += VIO<T>::ld(col - D_INNER_)     * w.z;
  if (l >= 2) acc += VIO<T>::ld(col - 2 * D_INNER_) * w.y;
  if (l >= 3) acc += VIO<T>::ld(col - 3 * D_INNER_) * w.x;
  VIO<T>::st(&xs[idx], acc / (1.f + __expf(-acc))); // silu
}

// ---------------------------------------------------------------------------
// x-projection: proj[m][e] = sum_k xs[m][k] * W_xproj[e][k],  e in [0,96).
// ---------------------------------------------------------------------------
template <typename T>
__global__ __launch_bounds__(256) void gemm_proj(
    const T* __restrict__ xs, const float* __restrict__ Wx,
    float* __restrict__ proj)
{
  __shared__ float As[16][68];
  __shared__ float Ws[96][68];
  const int m0 = blockIdx.x * 16;
  const int tid = threadIdx.x;
  const int r = tid & 15;           // compute row
  const int cg = tid >> 4;          // col group 0..15, cols cg*6 + j
  float acc[6] = {0.f, 0.f, 0.f, 0.f, 0.f, 0.f};
  const int ar = tid >> 4, ak = (tid & 15) * 4;     // A stage mapping

  for (int k0 = 0; k0 < D_INNER_; k0 += 64) {
    float4 av = VIO<T>::ld4(xs + (size_t)(m0 + ar) * D_INNER_ + k0 + ak);
    float4 wv[6];
#pragma unroll
    for (int q = 0; q < 6; ++q) {
      int g = tid + 256 * q;        // f4 index into 96x64 tile
      int wr = g >> 4, wk = (g & 15) * 4;
      wv[q] = *(const float4*)(Wx + (size_t)wr * D_INNER_ + k0 + wk);
    }
    __syncthreads();
    *(float4*)&As[ar][ak] = av;
#pragma unroll
    for (int q = 0; q < 6; ++q) {
      int g = tid + 256 * q;
      int wr = g >> 4, wk = (g & 15) * 4;
      *(float4*)&Ws[wr][wk] = wv[q];
    }
    __syncthreads();
    for (int kk = 0; kk < 64; kk += 4) {
      float4 a = *(const float4*)&As[r][kk];
#pragma unroll
      for (int j = 0; j < 6; ++j) {
        float4 w = *(const float4*)&Ws[cg * 6 + j][kk];
        acc[j] += a.x * w.x + a.y * w.y + a.z * w.z + a.w * w.w;
      }
    }
  }
#pragma unroll
  for (int j = 0; j < 6; ++j)
    proj[(size_t)(m0 + r) * XPROJ_N + cg * 6 + j] = acc[j];
}

// ---------------------------------------------------------------------------
// dt GEMM (K=64) + bias + stable softplus.
// ---------------------------------------------------------------------------
template <typename T>
__global__ __launch_bounds__(256) void gemm_dt_softplus(
    const float* __restrict__ proj, const float* __restrict__ Wdt,
    const float* __restrict__ bdt, T* __restrict__ dt)
{
  __shared__ float As[64][68];
  __shared__ float Bs[64][68];
  const int ntb = blockIdx.x & 31;          // D_INNER/64 = 32
  const int mt = blockIdx.x >> 5;
  const int m0 = mt << 6, n0 = ntb << 6;
  const int tid = threadIdx.x;
  const int tr = tid >> 4, tc = tid & 15;

#pragma unroll
  for (int q = 0; q < 4; ++q) {
    int f = tid + 256 * q;                  // f4 index into 64x64 tile
    int row = f >> 4, k4 = (f & 15) * 4;
    *(float4*)&As[row][k4] = *(const float4*)(proj + (size_t)(m0 + row) * XPROJ_N + k4);
    *(float4*)&Bs[row][k4] = *(const float4*)(Wdt + (size_t)(n0 + row) * DT_RANK_ + k4);
  }
  __syncthreads();

  float acc[4][4] = {{0.f, 0.f, 0.f, 0.f}, {0.f, 0.f, 0.f, 0.f},
                     {0.f, 0.f, 0.f, 0.f}, {0.f, 0.f, 0.f, 0.f}};
  for (int kk = 0; kk < 64; kk += 4) {
    float4 a[4], b[4];
#pragma unroll
    for (int i = 0; i < 4; ++i) a[i] = *(const float4*)&As[tr * 4 + i][kk];
#pragma unroll
    for (int j = 0; j < 4; ++j) b[j] = *(const float4*)&Bs[tc * 4 + j][kk];
#pragma unroll
    for (int i = 0; i < 4; ++i)
#pragma unroll
      for (int j = 0; j < 4; ++j)
        acc[i][j] += a[i].x * b[j].x + a[i].y * b[j].y +
                     a[i].z * b[j].z + a[i].w * b[j].w;
  }
#pragma unroll
  for (int i = 0; i < 4; ++i) {
#pragma unroll
    for (int j = 0; j < 4; ++j) {
      float z = acc[i][j] + bdt[n0 + tc * 4 + j];
      float sp = fmaxf(z, 0.f) + log1pf(__expf(-fabsf(z)));   // stable softplus
      VIO<T>::st(dt + (size_t)(m0 + tr * 4 + i) * D_INNER_ + n0 + tc * 4 + j, sp);
    }
  }
}

// ---------------------------------------------------------------------------
// Selective scan, one thread per (b, d, n).  16 lanes (one per state n) per
// channel d; y-reduction over n via shfl_xor.  Gating fused: zy holds z on
// input and is overwritten with y*silu(z) (only lane n==0 reads z[t][d] and
// then writes the same address from the same thread -> alias-safe).
// ---------------------------------------------------------------------------
template <typename T>
__global__ __launch_bounds__(256) void ssm_scan(
    const float* __restrict__ proj, const T* __restrict__ dt,
    const T* __restrict__ xs, T* __restrict__ zy,
    const float* __restrict__ A_log, const float* __restrict__ D_par)
{
  const int tid = threadIdx.x;
  const int n = tid & 15;
  const int dl = tid >> 4;                       // 0..15
  const int b = blockIdx.x >> 7;                 // 128 blocks per batch
  const int d = ((blockIdx.x & 127) << 4) + dl;
  const float An = -__expf(A_log[d * D_STATE_ + n]);
  const float Dd = D_par[d];
  float h = 0.f;
  const size_t tok0 = (size_t)b * SEQ;

  for (int l = 0; l < SEQ; ++l) {
    const size_t t = tok0 + l;
    const float dtv = VIO<T>::ld(&dt[t * D_INNER_ + d]);
    const float xsv = VIO<T>::ld(&xs[t * D_INNER_ + d]);
    const float Bn  = proj[t * XPROJ_N + DT_RANK_ + n];
    const float Cn  = proj[t * XPROJ_N + DT_RANK_ + D_STATE_ + n];
    h = h * __expf(dtv * An) + dtv * Bn * xsv;
    float c = h * Cn;
    c += __shfl_xor(c, 1);
    c += __shfl_xor(c, 2);
    c += __shfl_xor(c, 4);
    c += __shfl_xor(c, 8);
    if (n == 0) {
      const float zv = VIO<T>::ld(&zy[t * D_INNER_ + d]);
      const float g = zv / (1.f + __expf(-zv));  // silu(z)
      VIO<T>::st(&zy[t * D_INNER_ + d], (c + Dd * xsv) * g);
    }
  }
}

// ---------------------------------------------------------------------------
template <typename T>
static void run_pipeline(const float* x, const float* W_in, const float* W_conv,
                         const float* b_conv, const float* W_xp, const float* W_dt,
                         const float* b_dt, const float* A_log, const float* D_par,
                         const float* W_out, float* out,
                         T* xc, T* z, T* xs, float* proj, hipStream_t stream)
{
  T* dtb = xc;   // xc fully consumed by conv_silu before dt GEMM writes here
  T* zy  = z;    // scan overwrites z with gated y in place (alias-safe)

  // 1) xc = x @ W_in[0:d_inner]^T ; z = x @ W_in[d_inner:]^T
  gemm_nt<float, float, T><<<dim3((NTOK / 64) * (D_INNER_ / 64)), dim3(256), 0, stream>>>(
      x, W_in, xc, NTOK, D_INNER_, D_MODEL);
  gemm_nt<float, float, T><<<dim3((NTOK / 64) * (D_INNER_ / 64)), dim3(256), 0, stream>>>(
      x, W_in + (size_t)D_INNER_ * D_MODEL, z, NTOK, D_INNER_, D_MODEL);
  // 2) xs = silu(causal_dwconv(xc) + b_conv)
  conv_silu<T><<<dim3(NTOK * D_INNER_ / 256), dim3(256), 0, stream>>>(
      xc, W_conv, b_conv, xs);
  // 3) proj = xs @ W_xproj^T
  gemm_proj<T><<<dim3(NTOK / 16), dim3(256), 0, stream>>>(xs, W_xp, proj);
  // 4) dt = softplus(dt_low @ W_dt^T + b_dt)   (overwrites xc buffer)
  gemm_dt_softplus<T><<<dim3((NTOK / 64) * (D_INNER_ / 64)), dim3(256), 0, stream>>>(
      proj, W_dt, b_dt, dtb);
  // 5) selective scan + gating  (z -> y*silu(z) in place)
  ssm_scan<T><<<dim3(256), dim3(256), 0, stream>>>(
      proj, dtb, xs, zy, A_log, D_par);
  // 6) out = yg @ W_out^T
  gemm_nt<T, float, float><<<dim3((NTOK / 64) * (D_MODEL / 64)), dim3(256), 0, stream>>>(
      zy, W_out, out, NTOK, D_MODEL, D_INNER_);
}

extern "C" void kernel_launch(void* const* d_in, const int* in_sizes, int n_in,
                              void* d_out, int out_size, void* d_ws, size_t ws_size,
                              hipStream_t stream)
{
  const float* x      = (const float*)d_in[0];
  const float* W_in   = (const float*)d_in[1];
  const float* W_conv = (const float*)d_in[2];
  const float* b_conv = (const float*)d_in[3];
  const float* W_xp   = (const float*)d_in[4];
  const float* W_dt   = (const float*)d_in[5];
  const float* b_dt   = (const float*)d_in[6];
  const float* A_log  = (const float*)d_in[7];
  const float* D_par  = (const float*)d_in[8];
  const float* W_out  = (const float*)d_in[9];
  float* out = (float*)d_out;

  const size_t NE = (size_t)NTOK * D_INNER_;          // 4,194,304 elements
  const size_t need_f32 = (3 * NE + (size_t)NTOK * XPROJ_N) * sizeof(float); // 48.75 MiB

  if (ws_size >= need_f32) {
    // fp32 intermediates: [xc | z | xs | proj], dt aliases xc, yg aliases z
    float* xc   = (float*)d_ws;
    float* z    = xc + NE;
    float* xs   = z + NE;
    float* proj = xs + NE;
    run_pipeline<float>(x, W_in, W_conv, b_conv, W_xp, W_dt, b_dt, A_log, D_par,
                        W_out, out, xc, z, xs, proj, stream);
  } else {
    // bf16 intermediates (24.75 MiB): [xc | z | xs (ushort) | proj (float)]
    unsigned short* xc = (unsigned short*)d_ws;
    unsigned short* z  = xc + NE;
    unsigned short* xs = z + NE;
    float* proj = (float*)(xs + NE);
    run_pipeline<unsigned short>(x, W_in, W_conv, b_conv, W_xp, W_dt, b_dt, A_log,
                                 D_par, W_out, out, xc, z, xs, proj, stream);
  }
}

// Round 3
// 806.289 us; speedup vs baseline: 1.7215x; 1.7215x over previous
//
#include <hip/hip_runtime.h>
#include <math.h>

#define D_MODEL   1024
#define D_INNER_  2048
#define D_STATE_  16
#define DT_RANK_  64
#define SEQ       1024
#define NTOK      2048          // B * L
#define XPROJ_N   96            // dt_rank + 2*d_state
#define NC        16            // scan chunks per sequence
#define TC        64            // timesteps per chunk (NC*TC == SEQ)

// ---------------- bf16 storage helpers (fallback path) ---------------------
__device__ __forceinline__ float bf2f(unsigned short u) {
  return __uint_as_float(((unsigned int)u) << 16);
}
__device__ __forceinline__ unsigned short f2bf(float f) {
  unsigned int x = __float_as_uint(f);
  x += 0x7FFF + ((x >> 16) & 1);          // round-to-nearest-even
  return (unsigned short)(x >> 16);
}

template <typename T> struct VIO;
template <> struct VIO<float> {
  static __device__ __forceinline__ float4 ld4(const float* p) { return *(const float4*)p; }
  static __device__ __forceinline__ void st4(float* p, float4 v) { *(float4*)p = v; }
  static __device__ __forceinline__ float ld(const float* p) { return *p; }
  static __device__ __forceinline__ void st(float* p, float v) { *p = v; }
};
template <> struct VIO<unsigned short> {
  static __device__ __forceinline__ float4 ld4(const unsigned short* p) {
    ushort4 u = *(const ushort4*)p;
    return make_float4(bf2f(u.x), bf2f(u.y), bf2f(u.z), bf2f(u.w));
  }
  static __device__ __forceinline__ void st4(unsigned short* p, float4 v) {
    ushort4 u; u.x = f2bf(v.x); u.y = f2bf(v.y); u.z = f2bf(v.z); u.w = f2bf(v.w);
    *(ushort4*)p = u;
  }
  static __device__ __forceinline__ float ld(const unsigned short* p) { return bf2f(*p); }
  static __device__ __forceinline__ void st(unsigned short* p, float v) { *p = f2bf(v); }
};

// ---------------------------------------------------------------------------
// NT GEMM: C[M][N] = A[M][K] * B[N][K]^T.  M,N,K % 64 == 0.  (unchanged)
// ---------------------------------------------------------------------------
template <typename TA, typename TB, typename TC_>
__global__ __launch_bounds__(256) void gemm_nt(
    const TA* __restrict__ A, const TB* __restrict__ B,
    TC_* __restrict__ C, int M, int N, int K)
{
  __shared__ float As[64][68];
  __shared__ float Bs[64][68];
  const int ntiles = N >> 6;
  const int mt = blockIdx.x / ntiles, nt = blockIdx.x % ntiles;
  const int m0 = mt << 6, n0 = nt << 6;
  const int tid = threadIdx.x;
  const int lr = tid >> 2;              // load row 0..63
  const int lc = (tid & 3) << 4;        // load col start {0,16,32,48}
  const int tr = tid >> 4, tc = tid & 15;
  float acc[4][4] = {{0.f, 0.f, 0.f, 0.f}, {0.f, 0.f, 0.f, 0.f},
                     {0.f, 0.f, 0.f, 0.f}, {0.f, 0.f, 0.f, 0.f}};
  const TA* ag = A + (size_t)(m0 + lr) * K + lc;
  const TB* bg = B + (size_t)(n0 + lr) * K + lc;

  for (int k0 = 0; k0 < K; k0 += 64) {
    float4 a0 = VIO<TA>::ld4(ag + k0);
    float4 a1 = VIO<TA>::ld4(ag + k0 + 4);
    float4 a2 = VIO<TA>::ld4(ag + k0 + 8);
    float4 a3 = VIO<TA>::ld4(ag + k0 + 12);
    float4 b0 = VIO<TB>::ld4(bg + k0);
    float4 b1 = VIO<TB>::ld4(bg + k0 + 4);
    float4 b2 = VIO<TB>::ld4(bg + k0 + 8);
    float4 b3 = VIO<TB>::ld4(bg + k0 + 12);
    __syncthreads();                    // protect LDS reads of previous iter
    *(float4*)&As[lr][lc]      = a0;
    *(float4*)&As[lr][lc + 4]  = a1;
    *(float4*)&As[lr][lc + 8]  = a2;
    *(float4*)&As[lr][lc + 12] = a3;
    *(float4*)&Bs[lr][lc]      = b0;
    *(float4*)&Bs[lr][lc + 4]  = b1;
    *(float4*)&Bs[lr][lc + 8]  = b2;
    *(float4*)&Bs[lr][lc + 12] = b3;
    __syncthreads();
    for (int kk = 0; kk < 64; kk += 4) {
      float4 a[4], b[4];
#pragma unroll
      for (int i = 0; i < 4; ++i) a[i] = *(const float4*)&As[tr * 4 + i][kk];
#pragma unroll
      for (int j = 0; j < 4; ++j) b[j] = *(const float4*)&Bs[tc * 4 + j][kk];
#pragma unroll
      for (int i = 0; i < 4; ++i)
#pragma unroll
        for (int j = 0; j < 4; ++j)
          acc[i][j] += a[i].x * b[j].x + a[i].y * b[j].y +
                       a[i].z * b[j].z + a[i].w * b[j].w;
    }
  }
#pragma unroll
  for (int i = 0; i < 4; ++i) {
    float4 v = make_float4(acc[i][0], acc[i][1], acc[i][2], acc[i][3]);
    VIO<TC_>::st4(C + (size_t)(m0 + tr * 4 + i) * N + n0 + tc * 4, v);
  }
}

// ---------------------------------------------------------------------------
// Causal depthwise conv (k=4, left pad 3) + bias + silu.  (unchanged)
// ---------------------------------------------------------------------------
template <typename T>
__global__ __launch_bounds__(256) void conv_silu(
    const T* __restrict__ xc, const float* __restrict__ Wc,
    const float* __restrict__ bc, T* __restrict__ xs)
{
  const int idx = blockIdx.x * 256 + threadIdx.x;   // NTOK * D_INNER
  const int d = idx & (D_INNER_ - 1);
  const int t = idx >> 11;                          // token = b*L + l
  const int l = t & (SEQ - 1);
  const float4 w = *(const float4*)(Wc + d * 4);    // W_conv[d][0][0..3]
  const T* col = xc + (size_t)t * D_INNER_ + d;
  float acc = bc[d] + VIO<T>::ld(col) * w.w;
  if (l >= 1) acc += VIO<T>::ld(col - D_INNER_)     * w.z;
  if (l >= 2) acc += VIO<T>::ld(col - 2 * D_INNER_) * w.y;
  if (l >= 3) acc += VIO<T>::ld(col - 3 * D_INNER_) * w.x;
  VIO<T>::st(&xs[idx], acc / (1.f + __expf(-acc))); // silu
}

// ---------------------------------------------------------------------------
// x-projection: proj[m][e] = sum_k xs[m][k] * W_xproj[e][k].  (unchanged)
// ---------------------------------------------------------------------------
template <typename T>
__global__ __launch_bounds__(256) void gemm_proj(
    const T* __restrict__ xs, const float* __restrict__ Wx,
    float* __restrict__ proj)
{
  __shared__ float As[16][68];
  __shared__ float Ws[96][68];
  const int m0 = blockIdx.x * 16;
  const int tid = threadIdx.x;
  const int r = tid & 15;           // compute row
  const int cg = tid >> 4;          // col group 0..15, cols cg*6 + j
  float acc[6] = {0.f, 0.f, 0.f, 0.f, 0.f, 0.f};
  const int ar = tid >> 4, ak = (tid & 15) * 4;     // A stage mapping

  for (int k0 = 0; k0 < D_INNER_; k0 += 64) {
    float4 av = VIO<T>::ld4(xs + (size_t)(m0 + ar) * D_INNER_ + k0 + ak);
    float4 wv[6];
#pragma unroll
    for (int q = 0; q < 6; ++q) {
      int g = tid + 256 * q;        // f4 index into 96x64 tile
      int wr = g >> 4, wk = (g & 15) * 4;
      wv[q] = *(const float4*)(Wx + (size_t)wr * D_INNER_ + k0 + wk);
    }
    __syncthreads();
    *(float4*)&As[ar][ak] = av;
#pragma unroll
    for (int q = 0; q < 6; ++q) {
      int g = tid + 256 * q;
      int wr = g >> 4, wk = (g & 15) * 4;
      *(float4*)&Ws[wr][wk] = wv[q];
    }
    __syncthreads();
    for (int kk = 0; kk < 64; kk += 4) {
      float4 a = *(const float4*)&As[r][kk];
#pragma unroll
      for (int j = 0; j < 6; ++j) {
        float4 w = *(const float4*)&Ws[cg * 6 + j][kk];
        acc[j] += a.x * w.x + a.y * w.y + a.z * w.z + a.w * w.w;
      }
    }
  }
#pragma unroll
  for (int j = 0; j < 6; ++j)
    proj[(size_t)(m0 + r) * XPROJ_N + cg * 6 + j] = acc[j];
}

// ---------------------------------------------------------------------------
// dt GEMM (K=64) + bias + stable softplus.  (unchanged)
// ---------------------------------------------------------------------------
template <typename T>
__global__ __launch_bounds__(256) void gemm_dt_softplus(
    const float* __restrict__ proj, const float* __restrict__ Wdt,
    const float* __restrict__ bdt, T* __restrict__ dt)
{
  __shared__ float As[64][68];
  __shared__ float Bs[64][68];
  const int ntb = blockIdx.x & 31;          // D_INNER/64 = 32
  const int mt = blockIdx.x >> 5;
  const int m0 = mt << 6, n0 = ntb << 6;
  const int tid = threadIdx.x;
  const int tr = tid >> 4, tc = tid & 15;

#pragma unroll
  for (int q = 0; q < 4; ++q) {
    int f = tid + 256 * q;                  // f4 index into 64x64 tile
    int row = f >> 4, k4 = (f & 15) * 4;
    *(float4*)&As[row][k4] = *(const float4*)(proj + (size_t)(m0 + row) * XPROJ_N + k4);
    *(float4*)&Bs[row][k4] = *(const float4*)(Wdt + (size_t)(n0 + row) * DT_RANK_ + k4);
  }
  __syncthreads();

  float acc[4][4] = {{0.f, 0.f, 0.f, 0.f}, {0.f, 0.f, 0.f, 0.f},
                     {0.f, 0.f, 0.f, 0.f}, {0.f, 0.f, 0.f, 0.f}};
  for (int kk = 0; kk < 64; kk += 4) {
    float4 a[4], b[4];
#pragma unroll
    for (int i = 0; i < 4; ++i) a[i] = *(const float4*)&As[tr * 4 + i][kk];
#pragma unroll
    for (int j = 0; j < 4; ++j) b[j] = *(const float4*)&Bs[tc * 4 + j][kk];
#pragma unroll
    for (int i = 0; i < 4; ++i)
#pragma unroll
      for (int j = 0; j < 4; ++j)
        acc[i][j] += a[i].x * b[j].x + a[i].y * b[j].y +
                     a[i].z * b[j].z + a[i].w * b[j].w;
  }
#pragma unroll
  for (int i = 0; i < 4; ++i) {
#pragma unroll
    for (int j = 0; j < 4; ++j) {
      float z = acc[i][j] + bdt[n0 + tc * 4 + j];
      float sp = fmaxf(z, 0.f) + log1pf(__expf(-fabsf(z)));   // stable softplus
      VIO<T>::st(dt + (size_t)(m0 + tr * 4 + i) * D_INNER_ + n0 + tc * 4 + j, sp);
    }
  }
}

// ---------------------------------------------------------------------------
// Chunked selective scan.  h_{t} = exp(dt*A)*h_{t-1} + dt*B*xs is a diagonal
// affine recurrence -> associative.  Chunk c of TC steps collapses to
// (P = exp(sumA), q = local scan from h0=0).
//
// Pass A: per (b,c,d,n) compute (sumA, q).      grid 4096, 64 serial steps
// Pass B: scan chunk summaries over c; q[c] <- h_start(c) in place.
//                                               grid  256, 16 serial steps
// Pass C: re-run chunk from h_start, fused y-reduce + D-skip + silu(z) gate.
//                                               grid 4096, 64 serial steps
// Thread map (A/C): block = 16 channels x 16 states, lanes n within a
// 16-lane group share channel d (shfl_xor reduction over n).
// ---------------------------------------------------------------------------
template <typename T>
__global__ __launch_bounds__(256) void scan_chunk_reduce(
    const float* __restrict__ proj, const T* __restrict__ dt,
    const T* __restrict__ xs, const float* __restrict__ A_log,
    float* __restrict__ q, float* __restrict__ sumA)
{
  const int tid = threadIdx.x;
  const int n = tid & 15, dl = tid >> 4;
  const int dg = blockIdx.x & 127;
  const int c  = (blockIdx.x >> 7) & (NC - 1);
  const int b  = blockIdx.x >> 11;
  const int d = (dg << 4) + dl;
  const float An = -__expf(A_log[d * D_STATE_ + n]);
  float h = 0.f, sA = 0.f;
  const size_t t0 = (size_t)b * SEQ + (size_t)c * TC;
#pragma unroll 4
  for (int i = 0; i < TC; ++i) {
    const size_t t = t0 + i;
    const float dtv = VIO<T>::ld(&dt[t * D_INNER_ + d]);
    const float xsv = VIO<T>::ld(&xs[t * D_INNER_ + d]);
    const float Bn  = proj[t * XPROJ_N + DT_RANK_ + n];
    const float dA = dtv * An;
    sA += dA;
    h = __expf(dA) * h + dtv * Bn * xsv;
  }
  const size_t idx = ((size_t)(b * NC + c) * D_INNER_ + d) * D_STATE_ + n;
  q[idx] = h;
  sumA[idx] = sA;
}

__global__ __launch_bounds__(256) void scan_chunk_scan(
    float* __restrict__ q, const float* __restrict__ sumA)
{
  const int gid = blockIdx.x * 256 + threadIdx.x;   // (b*D_INNER+d)*16+n
  const int b = gid >> 15;                          // D_INNER*16 = 32768
  const int rest = gid & 32767;
  float h = 0.f;
#pragma unroll
  for (int c = 0; c < NC; ++c) {
    const size_t idx = ((size_t)(b * NC + c) << 15) + rest;
    const float P = __expf(sumA[idx]);
    const float qq = q[idx];
    q[idx] = h;                 // h at chunk start (read-then-write, same thread)
    h = P * h + qq;
  }
}

template <typename T>
__global__ __launch_bounds__(256) void scan_chunk_apply(
    const float* __restrict__ proj, const T* __restrict__ dt,
    const T* __restrict__ xs, T* __restrict__ zy,
    const float* __restrict__ A_log, const float* __restrict__ D_par,
    const float* __restrict__ hstart)
{
  const int tid = threadIdx.x;
  const int n = tid & 15, dl = tid >> 4;
  const int dg = blockIdx.x & 127;
  const int c  = (blockIdx.x >> 7) & (NC - 1);
  const int b  = blockIdx.x >> 11;
  const int d = (dg << 4) + dl;
  const float An = -__expf(A_log[d * D_STATE_ + n]);
  const float Dd = D_par[d];
  float h = hstart[((size_t)(b * NC + c) * D_INNER_ + d) * D_STATE_ + n];
  const size_t t0 = (size_t)b * SEQ + (size_t)c * TC;
#pragma unroll 2
  for (int i = 0; i < TC; ++i) {
    const size_t t = t0 + i;
    const float dtv = VIO<T>::ld(&dt[t * D_INNER_ + d]);
    const float xsv = VIO<T>::ld(&xs[t * D_INNER_ + d]);
    const float Bn  = proj[t * XPROJ_N + DT_RANK_ + n];
    const float Cn  = proj[t * XPROJ_N + DT_RANK_ + D_STATE_ + n];
    h = __expf(dtv * An) * h + dtv * Bn * xsv;
    float cacc = h * Cn;
    cacc += __shfl_xor(cacc, 1);
    cacc += __shfl_xor(cacc, 2);
    cacc += __shfl_xor(cacc, 4);
    cacc += __shfl_xor(cacc, 8);
    if (n == 0) {
      const float zv = VIO<T>::ld(&zy[t * D_INNER_ + d]);
      const float g = zv / (1.f + __expf(-zv));  // silu(z)
      VIO<T>::st(&zy[t * D_INNER_ + d], (cacc + Dd * xsv) * g);
    }
  }
}

// ---------------------------------------------------------------------------
template <typename T>
static void run_pipeline(const float* x, const float* W_in, const float* W_conv,
                         const float* b_conv, const float* W_xp, const float* W_dt,
                         const float* b_dt, const float* A_log, const float* D_par,
                         const float* W_out, float* out,
                         T* xc, T* z, T* xs, float* proj, hipStream_t stream)
{
  T* dtb = xc;   // xc fully consumed by conv_silu before dt GEMM writes here
  T* zy  = z;    // scan overwrites z with gated y in place (alias-safe)
  // scan chunk scratch lives in d_out: 2 * B*NC*D_INNER*D_STATE floats = 8 MB
  // == out_size exactly; final GEMM overwrites all of it afterwards.
  float* qbuf = out;
  float* sumA = out + (size_t)2 * NC * D_INNER_ * D_STATE_ / 2; // + 1M floats

  // 1) xc = x @ W_in[0:d_inner]^T ; z = x @ W_in[d_inner:]^T
  gemm_nt<float, float, T><<<dim3((NTOK / 64) * (D_INNER_ / 64)), dim3(256), 0, stream>>>(
      x, W_in, xc, NTOK, D_INNER_, D_MODEL);
  gemm_nt<float, float, T><<<dim3((NTOK / 64) * (D_INNER_ / 64)), dim3(256), 0, stream>>>(
      x, W_in + (size_t)D_INNER_ * D_MODEL, z, NTOK, D_INNER_, D_MODEL);
  // 2) xs = silu(causal_dwconv(xc) + b_conv)
  conv_silu<T><<<dim3(NTOK * D_INNER_ / 256), dim3(256), 0, stream>>>(
      xc, W_conv, b_conv, xs);
  // 3) proj = xs @ W_xproj^T
  gemm_proj<T><<<dim3(NTOK / 16), dim3(256), 0, stream>>>(xs, W_xp, proj);
  // 4) dt = softplus(dt_low @ W_dt^T + b_dt)   (overwrites xc buffer)
  gemm_dt_softplus<T><<<dim3((NTOK / 64) * (D_INNER_ / 64)), dim3(256), 0, stream>>>(
      proj, W_dt, b_dt, dtb);
  // 5) chunked selective scan + gating  (z -> y*silu(z) in place)
  scan_chunk_reduce<T><<<dim3(2 * NC * (D_INNER_ / 16)), dim3(256), 0, stream>>>(
      proj, dtb, xs, A_log, qbuf, sumA);
  scan_chunk_scan<<<dim3(2 * D_INNER_ * D_STATE_ / 256), dim3(256), 0, stream>>>(
      qbuf, sumA);
  scan_chunk_apply<T><<<dim3(2 * NC * (D_INNER_ / 16)), dim3(256), 0, stream>>>(
      proj, dtb, xs, zy, A_log, D_par, qbuf);
  // 6) out = yg @ W_out^T
  gemm_nt<T, float, float><<<dim3((NTOK / 64) * (D_MODEL / 64)), dim3(256), 0, stream>>>(
      zy, W_out, out, NTOK, D_MODEL, D_INNER_);
}

extern "C" void kernel_launch(void* const* d_in, const int* in_sizes, int n_in,
                              void* d_out, int out_size, void* d_ws, size_t ws_size,
                              hipStream_t stream)
{
  const float* x      = (const float*)d_in[0];
  const float* W_in   = (const float*)d_in[1];
  const float* W_conv = (const float*)d_in[2];
  const float* b_conv = (const float*)d_in[3];
  const float* W_xp   = (const float*)d_in[4];
  const float* W_dt   = (const float*)d_in[5];
  const float* b_dt   = (const float*)d_in[6];
  const float* A_log  = (const float*)d_in[7];
  const float* D_par  = (const float*)d_in[8];
  const float* W_out  = (const float*)d_in[9];
  float* out = (float*)d_out;

  const size_t NE = (size_t)NTOK * D_INNER_;          // 4,194,304 elements
  const size_t need_f32 = (3 * NE + (size_t)NTOK * XPROJ_N) * sizeof(float); // 48.75 MiB

  if (ws_size >= need_f32) {
    // fp32 intermediates: [xc | z | xs | proj], dt aliases xc, yg aliases z
    float* xc   = (float*)d_ws;
    float* z    = xc + NE;
    float* xs   = z + NE;
    float* proj = xs + NE;
    run_pipeline<float>(x, W_in, W_conv, b_conv, W_xp, W_dt, b_dt, A_log, D_par,
                        W_out, out, xc, z, xs, proj, stream);
  } else {
    // bf16 intermediates (24.75 MiB): [xc | z | xs (ushort) | proj (float)]
    unsigned short* xc = (unsigned short*)d_ws;
    unsigned short* z  = xc + NE;
    unsigned short* xs = z + NE;
    float* proj = (float*)(xs + NE);
    run_pipeline<unsigned short>(x, W_in, W_conv, b_conv, W_xp, W_dt, b_dt, A_log,
                                 D_par, W_out, out, xc, z, xs, proj, stream);
  }
}

// Round 4
// 457.494 us; speedup vs baseline: 3.0340x; 1.7624x over previous
//
#include <hip/hip_runtime.h>
#include <math.h>

#define D_MODEL   1024
#define D_INNER_  2048
#define D_STATE_  16
#define DT_RANK_  64
#define SEQ       1024
#define NTOK      2048          // B * L
#define XPROJ_N   96            // dt_rank + 2*d_state
#define NC        16            // scan chunks per sequence
#define TC        64            // timesteps per chunk (NC*TC == SEQ)

typedef __attribute__((ext_vector_type(8))) short s16x8;
typedef __attribute__((ext_vector_type(4))) float f32x4;

// ---------------- bf16 helpers ---------------------------------------------
__device__ __forceinline__ float bf2f(unsigned short u) {
  return __uint_as_float(((unsigned int)u) << 16);
}
__device__ __forceinline__ unsigned short f2bf(float f) {
  unsigned int x = __float_as_uint(f);
  x += 0x7FFF + ((x >> 16) & 1);          // round-to-nearest-even
  return (unsigned short)(x >> 16);
}

template <typename T> struct VIO;
template <> struct VIO<float> {
  static __device__ __forceinline__ float4 ld4(const float* p) { return *(const float4*)p; }
  static __device__ __forceinline__ float ld(const float* p) { return *p; }
  static __device__ __forceinline__ void st(float* p, float v) { *p = v; }
};
template <> struct VIO<unsigned short> {
  static __device__ __forceinline__ float4 ld4(const unsigned short* p) {
    ushort4 u = *(const ushort4*)p;
    return make_float4(bf2f(u.x), bf2f(u.y), bf2f(u.z), bf2f(u.w));
  }
  static __device__ __forceinline__ float ld(const unsigned short* p) { return bf2f(*p); }
  static __device__ __forceinline__ void st(unsigned short* p, float v) { *p = f2bf(v); }
};

// Load 16 consecutive elements as bf16 pairs (lo = e0..7, hi = e8..15).
template <typename T> struct LD16;
template <> struct LD16<float> {
  static __device__ __forceinline__ void go(const float* p, s16x8& lo, s16x8& hi) {
    float4 f0 = *(const float4*)p,       f1 = *(const float4*)(p + 4);
    float4 f2 = *(const float4*)(p + 8), f3 = *(const float4*)(p + 12);
    lo[0] = (short)f2bf(f0.x); lo[1] = (short)f2bf(f0.y);
    lo[2] = (short)f2bf(f0.z); lo[3] = (short)f2bf(f0.w);
    lo[4] = (short)f2bf(f1.x); lo[5] = (short)f2bf(f1.y);
    lo[6] = (short)f2bf(f1.z); lo[7] = (short)f2bf(f1.w);
    hi[0] = (short)f2bf(f2.x); hi[1] = (short)f2bf(f2.y);
    hi[2] = (short)f2bf(f2.z); hi[3] = (short)f2bf(f2.w);
    hi[4] = (short)f2bf(f3.x); hi[5] = (short)f2bf(f3.y);
    hi[6] = (short)f2bf(f3.z); hi[7] = (short)f2bf(f3.w);
  }
};
template <> struct LD16<unsigned short> {
  static __device__ __forceinline__ void go(const unsigned short* p, s16x8& lo, s16x8& hi) {
    lo = *(const s16x8*)p;
    hi = *(const s16x8*)(p + 8);
  }
};

// ---------------------------------------------------------------------------
// bf16 MFMA NT GEMM: C[M][N] = A[M][K] * B[N][K]^T, fp32 accumulate.
// 128x128 tile, 4 waves (2x2), each wave a 64x64 sub-tile = 4x4 frags of
// 16x16x32 MFMA.  BK=32.  A/B converted to bf16 during LDS staging.
// LDS rows padded to 40 bf16 (80 B): frag reads are ~2-way conflicts (free).
// M,N % 128 == 0, K % 32 == 0.
// ---------------------------------------------------------------------------
template <typename TA, typename TB, typename TCout>
__global__ __launch_bounds__(256) void gemm_mfma_nt(
    const TA* __restrict__ A, const TB* __restrict__ B,
    TCout* __restrict__ C, int M, int N, int K)
{
  __shared__ __align__(16) short As[128 * 40];
  __shared__ __align__(16) short Bs[128 * 40];
  const int ntiles = N >> 7;
  const int mt = blockIdx.x / ntiles, nt = blockIdx.x % ntiles;
  const int m0 = mt << 7, n0 = nt << 7;
  const int tid = threadIdx.x;
  const int lane = tid & 63;
  const int w = tid >> 6;                    // wave 0..3
  const int wm = (w >> 1) << 6, wn = (w & 1) << 6;
  const int lrow = lane & 15;                // own-matrix row/col within frag
  const int lk8 = (lane >> 4) << 3;          // k-chunk base {0,8,16,24}

  const int arow = tid >> 1;                 // staging row 0..127
  const int khalf = (tid & 1) << 4;          // k offset {0,16}
  const TA* pa = A + (size_t)(m0 + arow) * K + khalf;
  const TB* pb = B + (size_t)(n0 + arow) * K + khalf;

  f32x4 acc[4][4];
#pragma unroll
  for (int i = 0; i < 4; ++i)
#pragma unroll
    for (int j = 0; j < 4; ++j) acc[i][j] = (f32x4){0.f, 0.f, 0.f, 0.f};

  for (int k0 = 0; k0 < K; k0 += 32) {
    s16x8 va0, va1, vb0, vb1;
    LD16<TA>::go(pa + k0, va0, va1);
    LD16<TB>::go(pb + k0, vb0, vb1);
    __syncthreads();                         // previous iter's reads done
    *(s16x8*)&As[arow * 40 + khalf]     = va0;
    *(s16x8*)&As[arow * 40 + khalf + 8] = va1;
    *(s16x8*)&Bs[arow * 40 + khalf]     = vb0;
    *(s16x8*)&Bs[arow * 40 + khalf + 8] = vb1;
    __syncthreads();
    s16x8 af[4], bfr[4];
#pragma unroll
    for (int i = 0; i < 4; ++i)
      af[i] = *(const s16x8*)&As[(wm + i * 16 + lrow) * 40 + lk8];
#pragma unroll
    for (int j = 0; j < 4; ++j)
      bfr[j] = *(const s16x8*)&Bs[(wn + j * 16 + lrow) * 40 + lk8];
#pragma unroll
    for (int i = 0; i < 4; ++i)
#pragma unroll
      for (int j = 0; j < 4; ++j)
        acc[i][j] = __builtin_amdgcn_mfma_f32_16x16x32_bf16(
            af[i], bfr[j], acc[i][j], 0, 0, 0);
  }

  // epilogue: C/D layout col = lane&15 (B index), row = (lane>>4)*4+reg (A idx)
  const int crow0 = m0 + wm + (lane >> 4) * 4;
  const int ccol0 = n0 + wn + lrow;
#pragma unroll
  for (int i = 0; i < 4; ++i)
#pragma unroll
    for (int j = 0; j < 4; ++j)
#pragma unroll
      for (int r = 0; r < 4; ++r)
        VIO<TCout>::st(&C[(size_t)(crow0 + i * 16 + r) * N + ccol0 + j * 16],
                       acc[i][j][r]);
}

// ---------------------------------------------------------------------------
// Causal depthwise conv (k=4, left pad 3) + bias + silu.
// ---------------------------------------------------------------------------
template <typename TIn, typename TOut>
__global__ __launch_bounds__(256) void conv_silu(
    const TIn* __restrict__ xc, const float* __restrict__ Wc,
    const float* __restrict__ bc, TOut* __restrict__ xs)
{
  const int idx = blockIdx.x * 256 + threadIdx.x;   // NTOK * D_INNER
  const int d = idx & (D_INNER_ - 1);
  const int t = idx >> 11;                          // token = b*L + l
  const int l = t & (SEQ - 1);
  const float4 w = *(const float4*)(Wc + d * 4);    // W_conv[d][0][0..3]
  const TIn* col = xc + (size_t)t * D_INNER_ + d;
  float acc = bc[d] + VIO<TIn>::ld(col) * w.w;
  if (l >= 1) acc += VIO<TIn>::ld(col - D_INNER_)     * w.z;
  if (l >= 2) acc += VIO<TIn>::ld(col - 2 * D_INNER_) * w.y;
  if (l >= 3) acc += VIO<TIn>::ld(col - 3 * D_INNER_) * w.x;
  VIO<TOut>::st(&xs[idx], acc / (1.f + __expf(-acc))); // silu
}

// ---------------------------------------------------------------------------
// x-projection: proj[m][e] = sum_k xs[m][k] * W_xproj[e][k],  e in [0,96).
// ---------------------------------------------------------------------------
template <typename T>
__global__ __launch_bounds__(256) void gemm_proj(
    const T* __restrict__ xs, const float* __restrict__ Wx,
    float* __restrict__ proj)
{
  __shared__ float As[16][68];
  __shared__ float Ws[96][68];
  const int m0 = blockIdx.x * 16;
  const int tid = threadIdx.x;
  const int r = tid & 15;           // compute row
  const int cg = tid >> 4;          // col group 0..15, cols cg*6 + j
  float acc[6] = {0.f, 0.f, 0.f, 0.f, 0.f, 0.f};
  const int ar = tid >> 4, ak = (tid & 15) * 4;     // A stage mapping

  for (int k0 = 0; k0 < D_INNER_; k0 += 64) {
    float4 av = VIO<T>::ld4(xs + (size_t)(m0 + ar) * D_INNER_ + k0 + ak);
    float4 wv[6];
#pragma unroll
    for (int q = 0; q < 6; ++q) {
      int g = tid + 256 * q;        // f4 index into 96x64 tile
      int wr = g >> 4, wk = (g & 15) * 4;
      wv[q] = *(const float4*)(Wx + (size_t)wr * D_INNER_ + k0 + wk);
    }
    __syncthreads();
    *(float4*)&As[ar][ak] = av;
#pragma unroll
    for (int q = 0; q < 6; ++q) {
      int g = tid + 256 * q;
      int wr = g >> 4, wk = (g & 15) * 4;
      *(float4*)&Ws[wr][wk] = wv[q];
    }
    __syncthreads();
    for (int kk = 0; kk < 64; kk += 4) {
      float4 a = *(const float4*)&As[r][kk];
#pragma unroll
      for (int j = 0; j < 6; ++j) {
        float4 w = *(const float4*)&Ws[cg * 6 + j][kk];
        acc[j] += a.x * w.x + a.y * w.y + a.z * w.z + a.w * w.w;
      }
    }
  }
#pragma unroll
  for (int j = 0; j < 6; ++j)
    proj[(size_t)(m0 + r) * XPROJ_N + cg * 6 + j] = acc[j];
}

// ---------------------------------------------------------------------------
// dt GEMM (K=64) + bias + stable softplus.
// ---------------------------------------------------------------------------
template <typename T>
__global__ __launch_bounds__(256) void gemm_dt_softplus(
    const float* __restrict__ proj, const float* __restrict__ Wdt,
    const float* __restrict__ bdt, T* __restrict__ dt)
{
  __shared__ float As[64][68];
  __shared__ float Bs[64][68];
  const int ntb = blockIdx.x & 31;          // D_INNER/64 = 32
  const int mt = blockIdx.x >> 5;
  const int m0 = mt << 6, n0 = ntb << 6;
  const int tid = threadIdx.x;
  const int tr = tid >> 4, tc = tid & 15;

#pragma unroll
  for (int q = 0; q < 4; ++q) {
    int f = tid + 256 * q;                  // f4 index into 64x64 tile
    int row = f >> 4, k4 = (f & 15) * 4;
    *(float4*)&As[row][k4] = *(const float4*)(proj + (size_t)(m0 + row) * XPROJ_N + k4);
    *(float4*)&Bs[row][k4] = *(const float4*)(Wdt + (size_t)(n0 + row) * DT_RANK_ + k4);
  }
  __syncthreads();

  float acc[4][4] = {{0.f, 0.f, 0.f, 0.f}, {0.f, 0.f, 0.f, 0.f},
                     {0.f, 0.f, 0.f, 0.f}, {0.f, 0.f, 0.f, 0.f}};
  for (int kk = 0; kk < 64; kk += 4) {
    float4 a[4], b[4];
#pragma unroll
    for (int i = 0; i < 4; ++i) a[i] = *(const float4*)&As[tr * 4 + i][kk];
#pragma unroll
    for (int j = 0; j < 4; ++j) b[j] = *(const float4*)&Bs[tc * 4 + j][kk];
#pragma unroll
    for (int i = 0; i < 4; ++i)
#pragma unroll
      for (int j = 0; j < 4; ++j)
        acc[i][j] += a[i].x * b[j].x + a[i].y * b[j].y +
                     a[i].z * b[j].z + a[i].w * b[j].w;
  }
#pragma unroll
  for (int i = 0; i < 4; ++i) {
#pragma unroll
    for (int j = 0; j < 4; ++j) {
      float z = acc[i][j] + bdt[n0 + tc * 4 + j];
      float sp = fmaxf(z, 0.f) + log1pf(__expf(-fabsf(z)));   // stable softplus
      VIO<T>::st(dt + (size_t)(m0 + tr * 4 + i) * D_INNER_ + n0 + tc * 4 + j, sp);
    }
  }
}

// ---------------------------------------------------------------------------
// Chunked selective scan (3 passes).  TD = dt storage, TX = xs storage.
// ---------------------------------------------------------------------------
template <typename TD, typename TX>
__global__ __launch_bounds__(256) void scan_chunk_reduce(
    const float* __restrict__ proj, const TD* __restrict__ dt,
    const TX* __restrict__ xs, const float* __restrict__ A_log,
    float* __restrict__ q, float* __restrict__ sumA)
{
  const int tid = threadIdx.x;
  const int n = tid & 15, dl = tid >> 4;
  const int dg = blockIdx.x & 127;
  const int c  = (blockIdx.x >> 7) & (NC - 1);
  const int b  = blockIdx.x >> 11;
  const int d = (dg << 4) + dl;
  const float An = -__expf(A_log[d * D_STATE_ + n]);
  float h = 0.f, sA = 0.f;
  const size_t t0 = (size_t)b * SEQ + (size_t)c * TC;
#pragma unroll 4
  for (int i = 0; i < TC; ++i) {
    const size_t t = t0 + i;
    const float dtv = VIO<TD>::ld(&dt[t * D_INNER_ + d]);
    const float xsv = VIO<TX>::ld(&xs[t * D_INNER_ + d]);
    const float Bn  = proj[t * XPROJ_N + DT_RANK_ + n];
    const float dA = dtv * An;
    sA += dA;
    h = __expf(dA) * h + dtv * Bn * xsv;
  }
  const size_t idx = ((size_t)(b * NC + c) * D_INNER_ + d) * D_STATE_ + n;
  q[idx] = h;
  sumA[idx] = sA;
}

__global__ __launch_bounds__(256) void scan_chunk_scan(
    float* __restrict__ q, const float* __restrict__ sumA)
{
  const int gid = blockIdx.x * 256 + threadIdx.x;   // (b*D_INNER+d)*16+n
  const int b = gid >> 15;                          // D_INNER*16 = 32768
  const int rest = gid & 32767;
  float h = 0.f;
#pragma unroll
  for (int c = 0; c < NC; ++c) {
    const size_t idx = ((size_t)(b * NC + c) << 15) + rest;
    const float P = __expf(sumA[idx]);
    const float qq = q[idx];
    q[idx] = h;                 // h at chunk start (read-then-write, same thread)
    h = P * h + qq;
  }
}

template <typename TD, typename TX>
__global__ __launch_bounds__(256) void scan_chunk_apply(
    const float* __restrict__ proj, const TD* __restrict__ dt,
    const TX* __restrict__ xs, unsigned short* __restrict__ zy,
    const float* __restrict__ A_log, const float* __restrict__ D_par,
    const float* __restrict__ hstart)
{
  const int tid = threadIdx.x;
  const int n = tid & 15, dl = tid >> 4;
  const int dg = blockIdx.x & 127;
  const int c  = (blockIdx.x >> 7) & (NC - 1);
  const int b  = blockIdx.x >> 11;
  const int d = (dg << 4) + dl;
  const float An = -__expf(A_log[d * D_STATE_ + n]);
  const float Dd = D_par[d];
  float h = hstart[((size_t)(b * NC + c) * D_INNER_ + d) * D_STATE_ + n];
  const size_t t0 = (size_t)b * SEQ + (size_t)c * TC;
#pragma unroll 2
  for (int i = 0; i < TC; ++i) {
    const size_t t = t0 + i;
    const float dtv = VIO<TD>::ld(&dt[t * D_INNER_ + d]);
    const float xsv = VIO<TX>::ld(&xs[t * D_INNER_ + d]);
    const float Bn  = proj[t * XPROJ_N + DT_RANK_ + n];
    const float Cn  = proj[t * XPROJ_N + DT_RANK_ + D_STATE_ + n];
    h = __expf(dtv * An) * h + dtv * Bn * xsv;
    float cacc = h * Cn;
    cacc += __shfl_xor(cacc, 1);
    cacc += __shfl_xor(cacc, 2);
    cacc += __shfl_xor(cacc, 4);
    cacc += __shfl_xor(cacc, 8);
    if (n == 0) {
      const float zv = bf2f(zy[t * D_INNER_ + d]);
      const float g = zv / (1.f + __expf(-zv));  // silu(z)
      zy[t * D_INNER_ + d] = f2bf((cacc + Dd * xsv) * g);
    }
  }
}

// ---------------------------------------------------------------------------
// TD = dt storage type, TX = xs storage type.  xc/z/zy always bf16 (ushort).
template <typename TD, typename TX>
static void run_pipeline(const float* x, const float* W_in, const float* W_conv,
                         const float* b_conv, const float* W_xp, const float* W_dt,
                         const float* b_dt, const float* A_log, const float* D_par,
                         const float* W_out, float* out,
                         unsigned short* xc, unsigned short* z, TX* xs,
                         TD* dtb, float* proj, hipStream_t stream)
{
  unsigned short* zy = z;   // scan overwrites z with gated y in place
  // scan chunk scratch lives in d_out: 2 * 1M floats = 8 MiB == out bytes;
  // the out-proj GEMM overwrites all of d_out afterwards.
  float* qbuf = out;
  float* sumA = out + (size_t)2 * NC * D_INNER_ * D_STATE_ / 2; // + 1M floats

  // 1) xc = x @ W_in[0:d_inner]^T ; z = x @ W_in[d_inner:]^T   (bf16 MFMA)
  gemm_mfma_nt<float, float, unsigned short>
      <<<dim3((NTOK / 128) * (D_INNER_ / 128)), dim3(256), 0, stream>>>(
      x, W_in, xc, NTOK, D_INNER_, D_MODEL);
  gemm_mfma_nt<float, float, unsigned short>
      <<<dim3((NTOK / 128) * (D_INNER_ / 128)), dim3(256), 0, stream>>>(
      x, W_in + (size_t)D_INNER_ * D_MODEL, z, NTOK, D_INNER_, D_MODEL);
  // 2) xs = silu(causal_dwconv(xc) + b_conv)
  conv_silu<unsigned short, TX><<<dim3(NTOK * D_INNER_ / 256), dim3(256), 0, stream>>>(
      xc, W_conv, b_conv, xs);
  // 3) proj = xs @ W_xproj^T
  gemm_proj<TX><<<dim3(NTOK / 16), dim3(256), 0, stream>>>(xs, W_xp, proj);
  // 4) dt = softplus(dt_low @ W_dt^T + b_dt)
  gemm_dt_softplus<TD><<<dim3((NTOK / 64) * (D_INNER_ / 64)), dim3(256), 0, stream>>>(
      proj, W_dt, b_dt, dtb);
  // 5) chunked selective scan + gating  (z -> y*silu(z) in place)
  scan_chunk_reduce<TD, TX><<<dim3(2 * NC * (D_INNER_ / 16)), dim3(256), 0, stream>>>(
      proj, dtb, xs, A_log, qbuf, sumA);
  scan_chunk_scan<<<dim3(2 * D_INNER_ * D_STATE_ / 256), dim3(256), 0, stream>>>(
      qbuf, sumA);
  scan_chunk_apply<TD, TX><<<dim3(2 * NC * (D_INNER_ / 16)), dim3(256), 0, stream>>>(
      proj, dtb, xs, zy, A_log, D_par, qbuf);
  // 6) out = yg @ W_out^T   (bf16 MFMA)
  gemm_mfma_nt<unsigned short, float, float>
      <<<dim3((NTOK / 128) * (D_MODEL / 128)), dim3(256), 0, stream>>>(
      zy, W_out, out, NTOK, D_MODEL, D_INNER_);
}

extern "C" void kernel_launch(void* const* d_in, const int* in_sizes, int n_in,
                              void* d_out, int out_size, void* d_ws, size_t ws_size,
                              hipStream_t stream)
{
  const float* x      = (const float*)d_in[0];
  const float* W_in   = (const float*)d_in[1];
  const float* W_conv = (const float*)d_in[2];
  const float* b_conv = (const float*)d_in[3];
  const float* W_xp   = (const float*)d_in[4];
  const float* W_dt   = (const float*)d_in[5];
  const float* b_dt   = (const float*)d_in[6];
  const float* A_log  = (const float*)d_in[7];
  const float* D_par  = (const float*)d_in[8];
  const float* W_out  = (const float*)d_in[9];
  float* out = (float*)d_out;

  const size_t NE = (size_t)NTOK * D_INNER_;          // 4,194,304 elements
  // tier1: xc(bf16) z(bf16) xs(f32) dt(f32) proj(f32) = 48.75 MiB
  const size_t need_t1 = NE * 2 + NE * 2 + NE * 4 + NE * 4
                       + (size_t)NTOK * XPROJ_N * 4;

  if (ws_size >= need_t1) {
    unsigned short* xc = (unsigned short*)d_ws;
    unsigned short* z  = xc + NE;
    float* xs   = (float*)(z + NE);
    float* dtb  = xs + NE;
    float* proj = dtb + NE;
    run_pipeline<float, float>(x, W_in, W_conv, b_conv, W_xp, W_dt, b_dt, A_log,
                               D_par, W_out, out, xc, z, xs, dtb, proj, stream);
  } else {
    // tier2 (24.75 MiB): all bf16, dt aliases xc (xc dead after conv_silu)
    unsigned short* xc = (unsigned short*)d_ws;
    unsigned short* z  = xc + NE;
    unsigned short* xs = z + NE;
    float* proj = (float*)(xs + NE);
    run_pipeline<unsigned short, unsigned short>(
        x, W_in, W_conv, b_conv, W_xp, W_dt, b_dt, A_log,
        D_par, W_out, out, xc, z, xs, /*dtb=*/xc, proj, stream);
  }
}

// Round 5
// 383.882 us; speedup vs baseline: 3.6158x; 1.1918x over previous
//
#include <hip/hip_runtime.h>
#include <math.h>

#define D_MODEL   1024
#define D_INNER_  2048
#define D_STATE_  16
#define DT_RANK_  64
#define SEQ       1024
#define NTOK      2048          // B * L
#define XPROJ_N   96            // dt_rank + 2*d_state
#define NC        16            // scan chunks per sequence
#define TC        64            // timesteps per chunk (NC*TC == SEQ)
#define SPLITK    8             // K-splits for the x-projection
#define KCHUNK    (D_INNER_ / SPLITK)   // 256

typedef __attribute__((ext_vector_type(8))) short s16x8;
typedef __attribute__((ext_vector_type(4))) float f32x4;

// ---------------- bf16 helpers ---------------------------------------------
__device__ __forceinline__ float bf2f(unsigned short u) {
  return __uint_as_float(((unsigned int)u) << 16);
}
__device__ __forceinline__ unsigned short f2bf(float f) {
  unsigned int x = __float_as_uint(f);
  x += 0x7FFF + ((x >> 16) & 1);          // round-to-nearest-even
  return (unsigned short)(x >> 16);
}

template <typename T> struct VIO;
template <> struct VIO<float> {
  static __device__ __forceinline__ float4 ld4(const float* p) { return *(const float4*)p; }
  static __device__ __forceinline__ float ld(const float* p) { return *p; }
  static __device__ __forceinline__ void st(float* p, float v) { *p = v; }
};
template <> struct VIO<unsigned short> {
  static __device__ __forceinline__ float4 ld4(const unsigned short* p) {
    ushort4 u = *(const ushort4*)p;
    return make_float4(bf2f(u.x), bf2f(u.y), bf2f(u.z), bf2f(u.w));
  }
  static __device__ __forceinline__ float ld(const unsigned short* p) { return bf2f(*p); }
  static __device__ __forceinline__ void st(unsigned short* p, float v) { *p = f2bf(v); }
};

// Load 16 consecutive elements as bf16 pairs (lo = e0..7, hi = e8..15).
template <typename T> struct LD16;
template <> struct LD16<float> {
  static __device__ __forceinline__ void go(const float* p, s16x8& lo, s16x8& hi) {
    float4 f0 = *(const float4*)p,       f1 = *(const float4*)(p + 4);
    float4 f2 = *(const float4*)(p + 8), f3 = *(const float4*)(p + 12);
    lo[0] = (short)f2bf(f0.x); lo[1] = (short)f2bf(f0.y);
    lo[2] = (short)f2bf(f0.z); lo[3] = (short)f2bf(f0.w);
    lo[4] = (short)f2bf(f1.x); lo[5] = (short)f2bf(f1.y);
    lo[6] = (short)f2bf(f1.z); lo[7] = (short)f2bf(f1.w);
    hi[0] = (short)f2bf(f2.x); hi[1] = (short)f2bf(f2.y);
    hi[2] = (short)f2bf(f2.z); hi[3] = (short)f2bf(f2.w);
    hi[4] = (short)f2bf(f3.x); hi[5] = (short)f2bf(f3.y);
    hi[6] = (short)f2bf(f3.z); hi[7] = (short)f2bf(f3.w);
  }
};
template <> struct LD16<unsigned short> {
  static __device__ __forceinline__ void go(const unsigned short* p, s16x8& lo, s16x8& hi) {
    lo = *(const s16x8*)p;
    hi = *(const s16x8*)(p + 8);
  }
};

// ---------------------------------------------------------------------------
// bf16 MFMA NT GEMM: C[M][N] = A[M][K] * B[N][K]^T, fp32 accumulate.
// 128x128 tile, 4 waves (2x2), 4x4 frags of 16x16x32 MFMA.  (unchanged)
// ---------------------------------------------------------------------------
template <typename TA, typename TB, typename TCout>
__global__ __launch_bounds__(256) void gemm_mfma_nt(
    const TA* __restrict__ A, const TB* __restrict__ B,
    TCout* __restrict__ C, int M, int N, int K)
{
  __shared__ __align__(16) short As[128 * 40];
  __shared__ __align__(16) short Bs[128 * 40];
  const int ntiles = N >> 7;
  const int mt = blockIdx.x / ntiles, nt = blockIdx.x % ntiles;
  const int m0 = mt << 7, n0 = nt << 7;
  const int tid = threadIdx.x;
  const int lane = tid & 63;
  const int w = tid >> 6;                    // wave 0..3
  const int wm = (w >> 1) << 6, wn = (w & 1) << 6;
  const int lrow = lane & 15;                // own-matrix row/col within frag
  const int lk8 = (lane >> 4) << 3;          // k-chunk base {0,8,16,24}

  const int arow = tid >> 1;                 // staging row 0..127
  const int khalf = (tid & 1) << 4;          // k offset {0,16}
  const TA* pa = A + (size_t)(m0 + arow) * K + khalf;
  const TB* pb = B + (size_t)(n0 + arow) * K + khalf;

  f32x4 acc[4][4];
#pragma unroll
  for (int i = 0; i < 4; ++i)
#pragma unroll
    for (int j = 0; j < 4; ++j) acc[i][j] = (f32x4){0.f, 0.f, 0.f, 0.f};

  for (int k0 = 0; k0 < K; k0 += 32) {
    s16x8 va0, va1, vb0, vb1;
    LD16<TA>::go(pa + k0, va0, va1);
    LD16<TB>::go(pb + k0, vb0, vb1);
    __syncthreads();                         // previous iter's reads done
    *(s16x8*)&As[arow * 40 + khalf]     = va0;
    *(s16x8*)&As[arow * 40 + khalf + 8] = va1;
    *(s16x8*)&Bs[arow * 40 + khalf]     = vb0;
    *(s16x8*)&Bs[arow * 40 + khalf + 8] = vb1;
    __syncthreads();
    s16x8 af[4], bfr[4];
#pragma unroll
    for (int i = 0; i < 4; ++i)
      af[i] = *(const s16x8*)&As[(wm + i * 16 + lrow) * 40 + lk8];
#pragma unroll
    for (int j = 0; j < 4; ++j)
      bfr[j] = *(const s16x8*)&Bs[(wn + j * 16 + lrow) * 40 + lk8];
#pragma unroll
    for (int i = 0; i < 4; ++i)
#pragma unroll
      for (int j = 0; j < 4; ++j)
        acc[i][j] = __builtin_amdgcn_mfma_f32_16x16x32_bf16(
            af[i], bfr[j], acc[i][j], 0, 0, 0);
  }

  // epilogue: C/D layout col = lane&15 (B index), row = (lane>>4)*4+reg (A idx)
  const int crow0 = m0 + wm + (lane >> 4) * 4;
  const int ccol0 = n0 + wn + lrow;
#pragma unroll
  for (int i = 0; i < 4; ++i)
#pragma unroll
    for (int j = 0; j < 4; ++j)
#pragma unroll
      for (int r = 0; r < 4; ++r)
        VIO<TCout>::st(&C[(size_t)(crow0 + i * 16 + r) * N + ccol0 + j * 16],
                       acc[i][j][r]);
}

// ---------------------------------------------------------------------------
// Causal depthwise conv (k=4, left pad 3) + bias + silu.  (unchanged)
// ---------------------------------------------------------------------------
template <typename TIn, typename TOut>
__global__ __launch_bounds__(256) void conv_silu(
    const TIn* __restrict__ xc, const float* __restrict__ Wc,
    const float* __restrict__ bc, TOut* __restrict__ xs)
{
  const int idx = blockIdx.x * 256 + threadIdx.x;   // NTOK * D_INNER
  const int d = idx & (D_INNER_ - 1);
  const int t = idx >> 11;                          // token = b*L + l
  const int l = t & (SEQ - 1);
  const float4 w = *(const float4*)(Wc + d * 4);    // W_conv[d][0][0..3]
  const TIn* col = xc + (size_t)t * D_INNER_ + d;
  float acc = bc[d] + VIO<TIn>::ld(col) * w.w;
  if (l >= 1) acc += VIO<TIn>::ld(col - D_INNER_)     * w.z;
  if (l >= 2) acc += VIO<TIn>::ld(col - 2 * D_INNER_) * w.y;
  if (l >= 3) acc += VIO<TIn>::ld(col - 3 * D_INNER_) * w.x;
  VIO<TOut>::st(&xs[idx], acc / (1.f + __expf(-acc))); // silu
}

// ---------------------------------------------------------------------------
// x-projection, split-K: partial[s][m][e] = sum_{k in chunk s} xs[m][k]*Wx[e][k]
// Block = 16 rows x 96 cols over a 256-wide K chunk; grid = SPLITK * 128.
// ---------------------------------------------------------------------------
template <typename T>
__global__ __launch_bounds__(256) void gemm_proj_splitk(
    const T* __restrict__ xs, const float* __restrict__ Wx,
    float* __restrict__ partial)
{
  __shared__ float As[16][68];
  __shared__ float Ws[96][68];
  const int mtile = blockIdx.x & 127;
  const int s = blockIdx.x >> 7;            // K-split 0..7
  const int m0 = mtile * 16;
  const int kbase = s * KCHUNK;
  const int tid = threadIdx.x;
  const int r = tid & 15;           // compute row
  const int cg = tid >> 4;          // col group 0..15, cols cg*6 + j
  float acc[6] = {0.f, 0.f, 0.f, 0.f, 0.f, 0.f};
  const int ar = tid >> 4, ak = (tid & 15) * 4;     // A stage mapping

  for (int k0 = kbase; k0 < kbase + KCHUNK; k0 += 64) {
    float4 av = VIO<T>::ld4(xs + (size_t)(m0 + ar) * D_INNER_ + k0 + ak);
    float4 wv[6];
#pragma unroll
    for (int q = 0; q < 6; ++q) {
      int g = tid + 256 * q;        // f4 index into 96x64 tile
      int wr = g >> 4, wk = (g & 15) * 4;
      wv[q] = *(const float4*)(Wx + (size_t)wr * D_INNER_ + k0 + wk);
    }
    __syncthreads();
    *(float4*)&As[ar][ak] = av;
#pragma unroll
    for (int q = 0; q < 6; ++q) {
      int g = tid + 256 * q;
      int wr = g >> 4, wk = (g & 15) * 4;
      *(float4*)&Ws[wr][wk] = wv[q];
    }
    __syncthreads();
    for (int kk = 0; kk < 64; kk += 4) {
      float4 a = *(const float4*)&As[r][kk];
#pragma unroll
      for (int j = 0; j < 6; ++j) {
        float4 w = *(const float4*)&Ws[cg * 6 + j][kk];
        acc[j] += a.x * w.x + a.y * w.y + a.z * w.z + a.w * w.w;
      }
    }
  }
#pragma unroll
  for (int j = 0; j < 6; ++j)
    partial[((size_t)s * NTOK + m0 + r) * XPROJ_N + cg * 6 + j] = acc[j];
}

__global__ __launch_bounds__(256) void proj_reduce(
    const float* __restrict__ partial, float* __restrict__ proj)
{
  const int gid = blockIdx.x * 256 + threadIdx.x;   // NTOK*XPROJ_N = 196608
  float s = 0.f;
#pragma unroll
  for (int i = 0; i < SPLITK; ++i)
    s += partial[(size_t)i * NTOK * XPROJ_N + gid];
  proj[gid] = s;
}

// ---------------------------------------------------------------------------
// dt GEMM (K=64) + bias + stable softplus.  (unchanged)
// ---------------------------------------------------------------------------
template <typename T>
__global__ __launch_bounds__(256) void gemm_dt_softplus(
    const float* __restrict__ proj, const float* __restrict__ Wdt,
    const float* __restrict__ bdt, T* __restrict__ dt)
{
  __shared__ float As[64][68];
  __shared__ float Bs[64][68];
  const int ntb = blockIdx.x & 31;          // D_INNER/64 = 32
  const int mt = blockIdx.x >> 5;
  const int m0 = mt << 6, n0 = ntb << 6;
  const int tid = threadIdx.x;
  const int tr = tid >> 4, tc = tid & 15;

#pragma unroll
  for (int q = 0; q < 4; ++q) {
    int f = tid + 256 * q;                  // f4 index into 64x64 tile
    int row = f >> 4, k4 = (f & 15) * 4;
    *(float4*)&As[row][k4] = *(const float4*)(proj + (size_t)(m0 + row) * XPROJ_N + k4);
    *(float4*)&Bs[row][k4] = *(const float4*)(Wdt + (size_t)(n0 + row) * DT_RANK_ + k4);
  }
  __syncthreads();

  float acc[4][4] = {{0.f, 0.f, 0.f, 0.f}, {0.f, 0.f, 0.f, 0.f},
                     {0.f, 0.f, 0.f, 0.f}, {0.f, 0.f, 0.f, 0.f}};
  for (int kk = 0; kk < 64; kk += 4) {
    float4 a[4], b[4];
#pragma unroll
    for (int i = 0; i < 4; ++i) a[i] = *(const float4*)&As[tr * 4 + i][kk];
#pragma unroll
    for (int j = 0; j < 4; ++j) b[j] = *(const float4*)&Bs[tc * 4 + j][kk];
#pragma unroll
    for (int i = 0; i < 4; ++i)
#pragma unroll
      for (int j = 0; j < 4; ++j)
        acc[i][j] += a[i].x * b[j].x + a[i].y * b[j].y +
                     a[i].z * b[j].z + a[i].w * b[j].w;
  }
#pragma unroll
  for (int i = 0; i < 4; ++i) {
#pragma unroll
    for (int j = 0; j < 4; ++j) {
      float z = acc[i][j] + bdt[n0 + tc * 4 + j];
      float sp = fmaxf(z, 0.f) + log1pf(__expf(-fabsf(z)));   // stable softplus
      VIO<T>::st(dt + (size_t)(m0 + tr * 4 + i) * D_INNER_ + n0 + tc * 4 + j, sp);
    }
  }
}

// ---------------------------------------------------------------------------
// Chunked selective scan (3 passes).  TD = dt storage, TX = xs storage.
// ---------------------------------------------------------------------------
template <typename TD, typename TX>
__global__ __launch_bounds__(256) void scan_chunk_reduce(
    const float* __restrict__ proj, const TD* __restrict__ dt,
    const TX* __restrict__ xs, const float* __restrict__ A_log,
    float* __restrict__ q, float* __restrict__ sumA)
{
  const int tid = threadIdx.x;
  const int n = tid & 15, dl = tid >> 4;
  const int dg = blockIdx.x & 127;
  const int c  = (blockIdx.x >> 7) & (NC - 1);
  const int b  = blockIdx.x >> 11;
  const int d = (dg << 4) + dl;
  const float An = -__expf(A_log[d * D_STATE_ + n]);
  float h = 0.f, sA = 0.f;
  const size_t t0 = (size_t)b * SEQ + (size_t)c * TC;
#pragma unroll 4
  for (int i = 0; i < TC; ++i) {
    const size_t t = t0 + i;
    const float dtv = VIO<TD>::ld(&dt[t * D_INNER_ + d]);
    const float xsv = VIO<TX>::ld(&xs[t * D_INNER_ + d]);
    const float Bn  = proj[t * XPROJ_N + DT_RANK_ + n];
    const float dA = dtv * An;
    sA += dA;
    h = __expf(dA) * h + dtv * Bn * xsv;
  }
  const size_t idx = ((size_t)(b * NC + c) * D_INNER_ + d) * D_STATE_ + n;
  q[idx] = h;
  sumA[idx] = sA;
}

__global__ __launch_bounds__(256) void scan_chunk_scan(
    float* __restrict__ q, const float* __restrict__ sumA)
{
  const int gid = blockIdx.x * 256 + threadIdx.x;   // (b*D_INNER+d)*16+n
  const int b = gid >> 15;                          // D_INNER*16 = 32768
  const int rest = gid & 32767;
  float h = 0.f;
#pragma unroll
  for (int c = 0; c < NC; ++c) {
    const size_t idx = ((size_t)(b * NC + c) << 15) + rest;
    const float P = __expf(sumA[idx]);
    const float qq = q[idx];
    q[idx] = h;                 // h at chunk start (read-then-write, same thread)
    h = P * h + qq;
  }
}

template <typename TD, typename TX>
__global__ __launch_bounds__(256) void scan_chunk_apply(
    const float* __restrict__ proj, const TD* __restrict__ dt,
    const TX* __restrict__ xs, unsigned short* __restrict__ zy,
    const float* __restrict__ A_log, const float* __restrict__ D_par,
    const float* __restrict__ hstart)
{
  const int tid = threadIdx.x;
  const int n = tid & 15, dl = tid >> 4;
  const int dg = blockIdx.x & 127;
  const int c  = (blockIdx.x >> 7) & (NC - 1);
  const int b  = blockIdx.x >> 11;
  const int d = (dg << 4) + dl;
  const float An = -__expf(A_log[d * D_STATE_ + n]);
  const float Dd = D_par[d];
  float h = hstart[((size_t)(b * NC + c) * D_INNER_ + d) * D_STATE_ + n];
  const size_t t0 = (size_t)b * SEQ + (size_t)c * TC;
#pragma unroll 2
  for (int i = 0; i < TC; ++i) {
    const size_t t = t0 + i;
    const float dtv = VIO<TD>::ld(&dt[t * D_INNER_ + d]);
    const float xsv = VIO<TX>::ld(&xs[t * D_INNER_ + d]);
    const float Bn  = proj[t * XPROJ_N + DT_RANK_ + n];
    const float Cn  = proj[t * XPROJ_N + DT_RANK_ + D_STATE_ + n];
    h = __expf(dtv * An) * h + dtv * Bn * xsv;
    float cacc = h * Cn;
    cacc += __shfl_xor(cacc, 1);
    cacc += __shfl_xor(cacc, 2);
    cacc += __shfl_xor(cacc, 4);
    cacc += __shfl_xor(cacc, 8);
    if (n == 0) {
      const float zv = bf2f(zy[t * D_INNER_ + d]);
      const float g = zv / (1.f + __expf(-zv));  // silu(z)
      zy[t * D_INNER_ + d] = f2bf((cacc + Dd * xsv) * g);
    }
  }
}

// ---------------------------------------------------------------------------
// TD = dt storage type, TX = xs storage type.  xc/z/zy always bf16 (ushort).
template <typename TD, typename TX>
static void run_pipeline(const float* x, const float* W_in, const float* W_conv,
                         const float* b_conv, const float* W_xp, const float* W_dt,
                         const float* b_dt, const float* A_log, const float* D_par,
                         const float* W_out, float* out,
                         unsigned short* xc, unsigned short* z, TX* xs,
                         TD* dtb, float* proj, hipStream_t stream)
{
  unsigned short* zy = z;   // scan overwrites z with gated y in place
  // d_out doubles as scratch before step 6 overwrites it:
  //   step 3: split-K partials (SPLITK * NTOK * XPROJ_N = 6.3 MiB)
  //   step 5: scan chunk summaries q/sumA (2 * 1M floats = 8 MiB)
  float* partial = out;
  float* qbuf = out;
  float* sumA = out + (size_t)NC * D_INNER_ * D_STATE_;   // + 1M floats

  // 1) xc = x @ W_in[0:d_inner]^T ; z = x @ W_in[d_inner:]^T   (bf16 MFMA)
  gemm_mfma_nt<float, float, unsigned short>
      <<<dim3((NTOK / 128) * (D_INNER_ / 128)), dim3(256), 0, stream>>>(
      x, W_in, xc, NTOK, D_INNER_, D_MODEL);
  gemm_mfma_nt<float, float, unsigned short>
      <<<dim3((NTOK / 128) * (D_INNER_ / 128)), dim3(256), 0, stream>>>(
      x, W_in + (size_t)D_INNER_ * D_MODEL, z, NTOK, D_INNER_, D_MODEL);
  // 2) xs = silu(causal_dwconv(xc) + b_conv)
  conv_silu<unsigned short, TX><<<dim3(NTOK * D_INNER_ / 256), dim3(256), 0, stream>>>(
      xc, W_conv, b_conv, xs);
  // 3) proj = xs @ W_xproj^T   (split-K x8 into d_out, then reduce)
  gemm_proj_splitk<TX><<<dim3(SPLITK * (NTOK / 16)), dim3(256), 0, stream>>>(
      xs, W_xp, partial);
  proj_reduce<<<dim3(NTOK * XPROJ_N / 256), dim3(256), 0, stream>>>(partial, proj);
  // 4) dt = softplus(dt_low @ W_dt^T + b_dt)
  gemm_dt_softplus<TD><<<dim3((NTOK / 64) * (D_INNER_ / 64)), dim3(256), 0, stream>>>(
      proj, W_dt, b_dt, dtb);
  // 5) chunked selective scan + gating  (z -> y*silu(z) in place)
  scan_chunk_reduce<TD, TX><<<dim3(2 * NC * (D_INNER_ / 16)), dim3(256), 0, stream>>>(
      proj, dtb, xs, A_log, qbuf, sumA);
  scan_chunk_scan<<<dim3(2 * D_INNER_ * D_STATE_ / 256), dim3(256), 0, stream>>>(
      qbuf, sumA);
  scan_chunk_apply<TD, TX><<<dim3(2 * NC * (D_INNER_ / 16)), dim3(256), 0, stream>>>(
      proj, dtb, xs, zy, A_log, D_par, qbuf);
  // 6) out = yg @ W_out^T   (bf16 MFMA)
  gemm_mfma_nt<unsigned short, float, float>
      <<<dim3((NTOK / 128) * (D_MODEL / 128)), dim3(256), 0, stream>>>(
      zy, W_out, out, NTOK, D_MODEL, D_INNER_);
}

extern "C" void kernel_launch(void* const* d_in, const int* in_sizes, int n_in,
                              void* d_out, int out_size, void* d_ws, size_t ws_size,
                              hipStream_t stream)
{
  const float* x      = (const float*)d_in[0];
  const float* W_in   = (const float*)d_in[1];
  const float* W_conv = (const float*)d_in[2];
  const float* b_conv = (const float*)d_in[3];
  const float* W_xp   = (const float*)d_in[4];
  const float* W_dt   = (const float*)d_in[5];
  const float* b_dt   = (const float*)d_in[6];
  const float* A_log  = (const float*)d_in[7];
  const float* D_par  = (const float*)d_in[8];
  const float* W_out  = (const float*)d_in[9];
  float* out = (float*)d_out;

  const size_t NE = (size_t)NTOK * D_INNER_;          // 4,194,304 elements
  // tier1: xc(bf16) z(bf16) xs(f32) dt(f32) proj(f32) = 48.75 MiB
  const size_t need_t1 = NE * 2 + NE * 2 + NE * 4 + NE * 4
                       + (size_t)NTOK * XPROJ_N * 4;

  if (ws_size >= need_t1) {
    unsigned short* xc = (unsigned short*)d_ws;
    unsigned short* z  = xc + NE;
    float* xs   = (float*)(z + NE);
    float* dtb  = xs + NE;
    float* proj = dtb + NE;
    run_pipeline<float, float>(x, W_in, W_conv, b_conv, W_xp, W_dt, b_dt, A_log,
                               D_par, W_out, out, xc, z, xs, dtb, proj, stream);
  } else {
    // tier2 (24.75 MiB): all bf16, dt aliases xc (xc dead after conv_silu)
    unsigned short* xc = (unsigned short*)d_ws;
    unsigned short* z  = xc + NE;
    unsigned short* xs = z + NE;
    float* proj = (float*)(xs + NE);
    run_pipeline<unsigned short, unsigned short>(
        x, W_in, W_conv, b_conv, W_xp, W_dt, b_dt, A_log,
        D_par, W_out, out, xc, z, xs, /*dtb=*/xc, proj, stream);
  }
}

// Round 7
// 332.310 us; speedup vs baseline: 4.1770x; 1.1552x over previous
//
#include <hip/hip_runtime.h>
#include <math.h>

#define D_MODEL   1024
#define D_INNER_  2048
#define D_STATE_  16
#define DT_RANK_  64
#define SEQ       1024
#define NTOK      2048          // B * L
#define XPROJ_N   96            // dt_rank + 2*d_state
#define NC        16            // scan chunks per sequence
#define TC        64            // timesteps per chunk (NC*TC == SEQ)
#define SPLITK    8             // K-splits for the x-projection
#define KCHUNK    (D_INNER_ / SPLITK)   // 256

typedef __attribute__((ext_vector_type(8))) short s16x8;
typedef __attribute__((ext_vector_type(4))) float f32x4;

// ---------------- bf16 helpers ---------------------------------------------
__device__ __forceinline__ float bf2f(unsigned short u) {
  return __uint_as_float(((unsigned int)u) << 16);
}
__device__ __forceinline__ unsigned short f2bf(float f) {
  unsigned int x = __float_as_uint(f);
  x += 0x7FFF + ((x >> 16) & 1);          // round-to-nearest-even
  return (unsigned short)(x >> 16);
}

template <typename T> struct VIO;
template <> struct VIO<float> {
  static __device__ __forceinline__ float4 ld4(const float* p) { return *(const float4*)p; }
  static __device__ __forceinline__ float ld(const float* p) { return *p; }
  static __device__ __forceinline__ void st(float* p, float v) { *p = v; }
};
template <> struct VIO<unsigned short> {
  static __device__ __forceinline__ float4 ld4(const unsigned short* p) {
    ushort4 u = *(const ushort4*)p;
    return make_float4(bf2f(u.x), bf2f(u.y), bf2f(u.z), bf2f(u.w));
  }
  static __device__ __forceinline__ float ld(const unsigned short* p) { return bf2f(*p); }
  static __device__ __forceinline__ void st(unsigned short* p, float v) { *p = f2bf(v); }
};

// Load 16 consecutive elements as bf16 pairs (lo = e0..7, hi = e8..15).
template <typename T> struct LD16;
template <> struct LD16<float> {
  static __device__ __forceinline__ void go(const float* p, s16x8& lo, s16x8& hi) {
    float4 f0 = *(const float4*)p,       f1 = *(const float4*)(p + 4);
    float4 f2 = *(const float4*)(p + 8), f3 = *(const float4*)(p + 12);
    lo[0] = (short)f2bf(f0.x); lo[1] = (short)f2bf(f0.y);
    lo[2] = (short)f2bf(f0.z); lo[3] = (short)f2bf(f0.w);
    lo[4] = (short)f2bf(f1.x); lo[5] = (short)f2bf(f1.y);
    lo[6] = (short)f2bf(f1.z); lo[7] = (short)f2bf(f1.w);
    hi[0] = (short)f2bf(f2.x); hi[1] = (short)f2bf(f2.y);
    hi[2] = (short)f2bf(f2.z); hi[3] = (short)f2bf(f2.w);
    hi[4] = (short)f2bf(f3.x); hi[5] = (short)f2bf(f3.y);
    hi[6] = (short)f2bf(f3.z); hi[7] = (short)f2bf(f3.w);
  }
};
template <> struct LD16<unsigned short> {
  static __device__ __forceinline__ void go(const unsigned short* p, s16x8& lo, s16x8& hi) {
    lo = *(const s16x8*)p;
    hi = *(const s16x8*)(p + 8);
  }
};

// ---------------------------------------------------------------------------
// bf16 MFMA NT GEMM: C[M][N] = A[M][K] * B[N][K]^T, fp32 accumulate.
// 128x128 tile, 4 waves (2x2), 4x4 frags of 16x16x32 MFMA.  (unchanged)
// ---------------------------------------------------------------------------
template <typename TA, typename TB, typename TCout>
__global__ __launch_bounds__(256) void gemm_mfma_nt(
    const TA* __restrict__ A, const TB* __restrict__ B,
    TCout* __restrict__ C, int M, int N, int K)
{
  __shared__ __align__(16) short As[128 * 40];
  __shared__ __align__(16) short Bs[128 * 40];
  const int ntiles = N >> 7;
  const int mt = blockIdx.x / ntiles, nt = blockIdx.x % ntiles;
  const int m0 = mt << 7, n0 = nt << 7;
  const int tid = threadIdx.x;
  const int lane = tid & 63;
  const int w = tid >> 6;                    // wave 0..3
  const int wm = (w >> 1) << 6, wn = (w & 1) << 6;
  const int lrow = lane & 15;                // own-matrix row/col within frag
  const int lk8 = (lane >> 4) << 3;          // k-chunk base {0,8,16,24}

  const int arow = tid >> 1;                 // staging row 0..127
  const int khalf = (tid & 1) << 4;          // k offset {0,16}
  const TA* pa = A + (size_t)(m0 + arow) * K + khalf;
  const TB* pb = B + (size_t)(n0 + arow) * K + khalf;

  f32x4 acc[4][4];
#pragma unroll
  for (int i = 0; i < 4; ++i)
#pragma unroll
    for (int j = 0; j < 4; ++j) acc[i][j] = (f32x4){0.f, 0.f, 0.f, 0.f};

  for (int k0 = 0; k0 < K; k0 += 32) {
    s16x8 va0, va1, vb0, vb1;
    LD16<TA>::go(pa + k0, va0, va1);
    LD16<TB>::go(pb + k0, vb0, vb1);
    __syncthreads();                         // previous iter's reads done
    *(s16x8*)&As[arow * 40 + khalf]     = va0;
    *(s16x8*)&As[arow * 40 + khalf + 8] = va1;
    *(s16x8*)&Bs[arow * 40 + khalf]     = vb0;
    *(s16x8*)&Bs[arow * 40 + khalf + 8] = vb1;
    __syncthreads();
    s16x8 af[4], bfr[4];
#pragma unroll
    for (int i = 0; i < 4; ++i)
      af[i] = *(const s16x8*)&As[(wm + i * 16 + lrow) * 40 + lk8];
#pragma unroll
    for (int j = 0; j < 4; ++j)
      bfr[j] = *(const s16x8*)&Bs[(wn + j * 16 + lrow) * 40 + lk8];
#pragma unroll
    for (int i = 0; i < 4; ++i)
#pragma unroll
      for (int j = 0; j < 4; ++j)
        acc[i][j] = __builtin_amdgcn_mfma_f32_16x16x32_bf16(
            af[i], bfr[j], acc[i][j], 0, 0, 0);
  }

  // epilogue: C/D layout col = lane&15 (B index), row = (lane>>4)*4+reg (A idx)
  const int crow0 = m0 + wm + (lane >> 4) * 4;
  const int ccol0 = n0 + wn + lrow;
#pragma unroll
  for (int i = 0; i < 4; ++i)
#pragma unroll
    for (int j = 0; j < 4; ++j)
#pragma unroll
      for (int r = 0; r < 4; ++r)
        VIO<TCout>::st(&C[(size_t)(crow0 + i * 16 + r) * N + ccol0 + j * 16],
                       acc[i][j][r]);
}

// ---------------------------------------------------------------------------
// Causal depthwise conv (k=4, left pad 3) + bias + silu.  (unchanged)
// ---------------------------------------------------------------------------
template <typename TIn, typename TOut>
__global__ __launch_bounds__(256) void conv_silu(
    const TIn* __restrict__ xc, const float* __restrict__ Wc,
    const float* __restrict__ bc, TOut* __restrict__ xs)
{
  const int idx = blockIdx.x * 256 + threadIdx.x;   // NTOK * D_INNER
  const int d = idx & (D_INNER_ - 1);
  const int t = idx >> 11;                          // token = b*L + l
  const int l = t & (SEQ - 1);
  const float4 w = *(const float4*)(Wc + d * 4);    // W_conv[d][0][0..3]
  const TIn* col = xc + (size_t)t * D_INNER_ + d;
  float acc = bc[d] + VIO<TIn>::ld(col) * w.w;
  if (l >= 1) acc += VIO<TIn>::ld(col - D_INNER_)     * w.z;
  if (l >= 2) acc += VIO<TIn>::ld(col - 2 * D_INNER_) * w.y;
  if (l >= 3) acc += VIO<TIn>::ld(col - 3 * D_INNER_) * w.x;
  VIO<TOut>::st(&xs[idx], acc / (1.f + __expf(-acc))); // silu
}

// ---------------------------------------------------------------------------
// x-projection, split-K.  (unchanged)
// ---------------------------------------------------------------------------
template <typename T>
__global__ __launch_bounds__(256) void gemm_proj_splitk(
    const T* __restrict__ xs, const float* __restrict__ Wx,
    float* __restrict__ partial)
{
  __shared__ float As[16][68];
  __shared__ float Ws[96][68];
  const int mtile = blockIdx.x & 127;
  const int s = blockIdx.x >> 7;            // K-split 0..7
  const int m0 = mtile * 16;
  const int kbase = s * KCHUNK;
  const int tid = threadIdx.x;
  const int r = tid & 15;           // compute row
  const int cg = tid >> 4;          // col group 0..15, cols cg*6 + j
  float acc[6] = {0.f, 0.f, 0.f, 0.f, 0.f, 0.f};
  const int ar = tid >> 4, ak = (tid & 15) * 4;     // A stage mapping

  for (int k0 = kbase; k0 < kbase + KCHUNK; k0 += 64) {
    float4 av = VIO<T>::ld4(xs + (size_t)(m0 + ar) * D_INNER_ + k0 + ak);
    float4 wv[6];
#pragma unroll
    for (int q = 0; q < 6; ++q) {
      int g = tid + 256 * q;        // f4 index into 96x64 tile
      int wr = g >> 4, wk = (g & 15) * 4;
      wv[q] = *(const float4*)(Wx + (size_t)wr * D_INNER_ + k0 + wk);
    }
    __syncthreads();
    *(float4*)&As[ar][ak] = av;
#pragma unroll
    for (int q = 0; q < 6; ++q) {
      int g = tid + 256 * q;
      int wr = g >> 4, wk = (g & 15) * 4;
      *(float4*)&Ws[wr][wk] = wv[q];
    }
    __syncthreads();
    for (int kk = 0; kk < 64; kk += 4) {
      float4 a = *(const float4*)&As[r][kk];
#pragma unroll
      for (int j = 0; j < 6; ++j) {
        float4 w = *(const float4*)&Ws[cg * 6 + j][kk];
        acc[j] += a.x * w.x + a.y * w.y + a.z * w.z + a.w * w.w;
      }
    }
  }
#pragma unroll
  for (int j = 0; j < 6; ++j)
    partial[((size_t)s * NTOK + m0 + r) * XPROJ_N + cg * 6 + j] = acc[j];
}

__global__ __launch_bounds__(256) void proj_reduce(
    const float* __restrict__ partial, float* __restrict__ proj)
{
  const int gid = blockIdx.x * 256 + threadIdx.x;   // NTOK*XPROJ_N = 196608
  float s = 0.f;
#pragma unroll
  for (int i = 0; i < SPLITK; ++i)
    s += partial[(size_t)i * NTOK * XPROJ_N + gid];
  proj[gid] = s;
}

// ---------------------------------------------------------------------------
// dt GEMM (K=64) + bias + stable softplus.  (unchanged)
// ---------------------------------------------------------------------------
template <typename T>
__global__ __launch_bounds__(256) void gemm_dt_softplus(
    const float* __restrict__ proj, const float* __restrict__ Wdt,
    const float* __restrict__ bdt, T* __restrict__ dt)
{
  __shared__ float As[64][68];
  __shared__ float Bs[64][68];
  const int ntb = blockIdx.x & 31;          // D_INNER/64 = 32
  const int mt = blockIdx.x >> 5;
  const int m0 = mt << 6, n0 = ntb << 6;
  const int tid = threadIdx.x;
  const int tr = tid >> 4, tc = tid & 15;

#pragma unroll
  for (int q = 0; q < 4; ++q) {
    int f = tid + 256 * q;                  // f4 index into 64x64 tile
    int row = f >> 4, k4 = (f & 15) * 4;
    *(float4*)&As[row][k4] = *(const float4*)(proj + (size_t)(m0 + row) * XPROJ_N + k4);
    *(float4*)&Bs[row][k4] = *(const float4*)(Wdt + (size_t)(n0 + row) * DT_RANK_ + k4);
  }
  __syncthreads();

  float acc[4][4] = {{0.f, 0.f, 0.f, 0.f}, {0.f, 0.f, 0.f, 0.f},
                     {0.f, 0.f, 0.f, 0.f}, {0.f, 0.f, 0.f, 0.f}};
  for (int kk = 0; kk < 64; kk += 4) {
    float4 a[4], b[4];
#pragma unroll
    for (int i = 0; i < 4; ++i) a[i] = *(const float4*)&As[tr * 4 + i][kk];
#pragma unroll
    for (int j = 0; j < 4; ++j) b[j] = *(const float4*)&Bs[tc * 4 + j][kk];
#pragma unroll
    for (int i = 0; i < 4; ++i)
#pragma unroll
      for (int j = 0; j < 4; ++j)
        acc[i][j] += a[i].x * b[j].x + a[i].y * b[j].y +
                     a[i].z * b[j].z + a[i].w * b[j].w;
  }
#pragma unroll
  for (int i = 0; i < 4; ++i) {
#pragma unroll
    for (int j = 0; j < 4; ++j) {
      float z = acc[i][j] + bdt[n0 + tc * 4 + j];
      float sp = fmaxf(z, 0.f) + log1pf(__expf(-fabsf(z)));   // stable softplus
      VIO<T>::st(dt + (size_t)(m0 + tr * 4 + i) * D_INNER_ + n0 + tc * 4 + j, sp);
    }
  }
}

// ---------------------------------------------------------------------------
// Register-state chunked scan.  Thread per (b, chunk, d), h[16] in VGPRs.
// B/C rows staged in LDS, copied per-step into contiguous local arrays
// (Bv[16]/Cv[16], constant-indexed -> registers).  No cross-lane ops.
// ---------------------------------------------------------------------------
template <typename TD, typename TX>
__global__ __launch_bounds__(256) void scan2_reduce(
    const float* __restrict__ proj, const TD* __restrict__ dt,
    const TX* __restrict__ xs, const float* __restrict__ A_log,
    float* __restrict__ q, float* __restrict__ sdt)
{
  __shared__ float Bsh[TC][16];
  const int tid = threadIdx.x;
  const int b = blockIdx.x >> 7;
  const int c = (blockIdx.x >> 3) & (NC - 1);
  const int d = ((blockIdx.x & 7) << 8) + tid;
  const size_t tok0 = (size_t)b * SEQ + (size_t)c * TC;
  { // stage B rows: 64 x 16 floats, 1 float4 per thread
    const int e = tid * 4, t = e >> 4, col = e & 15;
    *(float4*)&Bsh[t][col] = *(const float4*)&proj[(tok0 + t) * XPROJ_N + DT_RANK_ + col];
  }
  float An[D_STATE_];
#pragma unroll
  for (int n = 0; n < D_STATE_; ++n) An[n] = -__expf(A_log[d * D_STATE_ + n]);
  __syncthreads();

  float h[D_STATE_];
#pragma unroll
  for (int n = 0; n < D_STATE_; ++n) h[n] = 0.f;
  float s = 0.f;
  for (int t = 0; t < TC; ++t) {
    const size_t tt = tok0 + t;
    const float dtv = VIO<TD>::ld(&dt[tt * D_INNER_ + d]);
    const float xsv = VIO<TX>::ld(&xs[tt * D_INNER_ + d]);
    s += dtv;
    const float dx = dtv * xsv;
    float Bv[D_STATE_];
#pragma unroll
    for (int k = 0; k < 4; ++k)
      *(float4*)&Bv[4 * k] = *(const float4*)&Bsh[t][4 * k];
#pragma unroll
    for (int n = 0; n < D_STATE_; ++n)
      h[n] = __expf(dtv * An[n]) * h[n] + dx * Bv[n];
  }
  const size_t idx = (size_t)(b * NC + c) * D_INNER_ + d;
#pragma unroll
  for (int k = 0; k < 4; ++k)
    *(float4*)&q[idx * D_STATE_ + 4 * k] =
        make_float4(h[4 * k], h[4 * k + 1], h[4 * k + 2], h[4 * k + 3]);
  sdt[idx] = s;
}

__global__ __launch_bounds__(256) void scan2_mid(
    float* __restrict__ q, const float* __restrict__ sdt,
    const float* __restrict__ A_log)
{
  const int gid = blockIdx.x * 256 + threadIdx.x;   // (b*D_INNER+d)*16+n
  const int n = gid & 15;
  const int d = (gid >> 4) & (D_INNER_ - 1);
  const int b = gid >> 15;
  const float An = -__expf(A_log[d * D_STATE_ + n]);
  float h = 0.f;
#pragma unroll
  for (int c = 0; c < NC; ++c) {
    const size_t idx = (size_t)(b * NC + c) * D_INNER_ + d;
    const float P = __expf(An * sdt[idx]);
    const float qq = q[idx * D_STATE_ + n];
    q[idx * D_STATE_ + n] = h;        // h at chunk start
    h = P * h + qq;
  }
}

template <typename TD, typename TX>
__global__ __launch_bounds__(256) void scan2_apply(
    const float* __restrict__ proj, const TD* __restrict__ dt,
    const TX* __restrict__ xs, unsigned short* __restrict__ zy,
    const float* __restrict__ A_log, const float* __restrict__ D_par,
    const float* __restrict__ hstart)
{
  __shared__ float BC[TC][32];      // [t][0..15] = B, [t][16..31] = C
  const int tid = threadIdx.x;
  const int b = blockIdx.x >> 7;
  const int c = (blockIdx.x >> 3) & (NC - 1);
  const int d = ((blockIdx.x & 7) << 8) + tid;
  const size_t tok0 = (size_t)b * SEQ + (size_t)c * TC;
  { // stage B+C: 64 x 32 floats, 2 float4 per thread
    const int e = tid * 8, t = e >> 5, col = e & 31;
    const float* src = &proj[(tok0 + t) * XPROJ_N + DT_RANK_ + col];
    *(float4*)&BC[t][col]     = *(const float4*)src;
    *(float4*)&BC[t][col + 4] = *(const float4*)(src + 4);
  }
  float An[D_STATE_];
#pragma unroll
  for (int n = 0; n < D_STATE_; ++n) An[n] = -__expf(A_log[d * D_STATE_ + n]);
  const float Dd = D_par[d];
  const size_t idx = (size_t)(b * NC + c) * D_INNER_ + d;
  float h[D_STATE_];
#pragma unroll
  for (int k = 0; k < 4; ++k) {
    float4 v = *(const float4*)&hstart[idx * D_STATE_ + 4 * k];
    h[4 * k] = v.x; h[4 * k + 1] = v.y; h[4 * k + 2] = v.z; h[4 * k + 3] = v.w;
  }
  __syncthreads();

  for (int t = 0; t < TC; ++t) {
    const size_t tt = tok0 + t;
    const float dtv = VIO<TD>::ld(&dt[tt * D_INNER_ + d]);
    const float xsv = VIO<TX>::ld(&xs[tt * D_INNER_ + d]);
    const float zv  = bf2f(zy[tt * D_INNER_ + d]);
    const float dx = dtv * xsv;
    float Bv[D_STATE_], Cv[D_STATE_];
#pragma unroll
    for (int k = 0; k < 4; ++k) {
      *(float4*)&Bv[4 * k] = *(const float4*)&BC[t][4 * k];
      *(float4*)&Cv[4 * k] = *(const float4*)&BC[t][16 + 4 * k];
    }
    float y = 0.f;
#pragma unroll
    for (int n = 0; n < D_STATE_; ++n) {
      h[n] = __expf(dtv * An[n]) * h[n] + dx * Bv[n];
      y += h[n] * Cv[n];
    }
    const float g = zv / (1.f + __expf(-zv));      // silu(z)
    zy[tt * D_INNER_ + d] = f2bf((y + Dd * xsv) * g);
  }
}

// ---------------------------------------------------------------------------
// TD = dt storage type, TX = xs storage type.  xc/z/zy always bf16 (ushort).
template <typename TD, typename TX>
static void run_pipeline(const float* x, const float* W_in, const float* W_conv,
                         const float* b_conv, const float* W_xp, const float* W_dt,
                         const float* b_dt, const float* A_log, const float* D_par,
                         const float* W_out, float* out,
                         unsigned short* xc, unsigned short* z, TX* xs,
                         TD* dtb, float* proj, hipStream_t stream)
{
  unsigned short* zy = z;   // scan overwrites z with gated y in place
  // d_out doubles as scratch before step 6 overwrites it:
  //   step 3: split-K partials (6.3 MiB)
  //   step 5: q (4 MiB) + sdt (256 KiB)
  float* partial = out;
  float* qbuf = out;
  float* sdt  = out + (size_t)2 * NC * D_INNER_ * D_STATE_;   // + 1M floats

  // 1) xc = x @ W_in[0:d_inner]^T ; z = x @ W_in[d_inner:]^T   (bf16 MFMA)
  gemm_mfma_nt<float, float, unsigned short>
      <<<dim3((NTOK / 128) * (D_INNER_ / 128)), dim3(256), 0, stream>>>(
      x, W_in, xc, NTOK, D_INNER_, D_MODEL);
  gemm_mfma_nt<float, float, unsigned short>
      <<<dim3((NTOK / 128) * (D_INNER_ / 128)), dim3(256), 0, stream>>>(
      x, W_in + (size_t)D_INNER_ * D_MODEL, z, NTOK, D_INNER_, D_MODEL);
  // 2) xs = silu(causal_dwconv(xc) + b_conv)
  conv_silu<unsigned short, TX><<<dim3(NTOK * D_INNER_ / 256), dim3(256), 0, stream>>>(
      xc, W_conv, b_conv, xs);
  // 3) proj = xs @ W_xproj^T   (split-K x8 into d_out, then reduce)
  gemm_proj_splitk<TX><<<dim3(SPLITK * (NTOK / 16)), dim3(256), 0, stream>>>(
      xs, W_xp, partial);
  proj_reduce<<<dim3(NTOK * XPROJ_N / 256), dim3(256), 0, stream>>>(partial, proj);
  // 4) dt = softplus(dt_low @ W_dt^T + b_dt)
  gemm_dt_softplus<TD><<<dim3((NTOK / 64) * (D_INNER_ / 64)), dim3(256), 0, stream>>>(
      proj, W_dt, b_dt, dtb);
  // 5) register-state chunked scan + gating  (z -> y*silu(z) in place)
  scan2_reduce<TD, TX><<<dim3(2 * NC * (D_INNER_ / 256)), dim3(256), 0, stream>>>(
      proj, dtb, xs, A_log, qbuf, sdt);
  scan2_mid<<<dim3(2 * D_INNER_ * D_STATE_ / 256), dim3(256), 0, stream>>>(
      qbuf, sdt, A_log);
  scan2_apply<TD, TX><<<dim3(2 * NC * (D_INNER_ / 256)), dim3(256), 0, stream>>>(
      proj, dtb, xs, zy, A_log, D_par, qbuf);
  // 6) out = yg @ W_out^T   (bf16 MFMA)
  gemm_mfma_nt<unsigned short, float, float>
      <<<dim3((NTOK / 128) * (D_MODEL / 128)), dim3(256), 0, stream>>>(
      zy, W_out, out, NTOK, D_MODEL, D_INNER_);
}

extern "C" void kernel_launch(void* const* d_in, const int* in_sizes, int n_in,
                              void* d_out, int out_size, void* d_ws, size_t ws_size,
                              hipStream_t stream)
{
  const float* x      = (const float*)d_in[0];
  const float* W_in   = (const float*)d_in[1];
  const float* W_conv = (const float*)d_in[2];
  const float* b_conv = (const float*)d_in[3];
  const float* W_xp   = (const float*)d_in[4];
  const float* W_dt   = (const float*)d_in[5];
  const float* b_dt   = (const float*)d_in[6];
  const float* A_log  = (const float*)d_in[7];
  const float* D_par  = (const float*)d_in[8];
  const float* W_out  = (const float*)d_in[9];
  float* out = (float*)d_out;

  const size_t NE = (size_t)NTOK * D_INNER_;          // 4,194,304 elements
  // tier1: xc(bf16) z(bf16) xs(f32) dt(f32) proj(f32) = 48.75 MiB
  const size_t need_t1 = NE * 2 + NE * 2 + NE * 4 + NE * 4
                       + (size_t)NTOK * XPROJ_N * 4;

  if (ws_size >= need_t1) {
    unsigned short* xc = (unsigned short*)d_ws;
    unsigned short* z  = xc + NE;
    float* xs   = (float*)(z + NE);
    float* dtb  = xs + NE;
    float* proj = dtb + NE;
    run_pipeline<float, float>(x, W_in, W_conv, b_conv, W_xp, W_dt, b_dt, A_log,
                               D_par, W_out, out, xc, z, xs, dtb, proj, stream);
  } else {
    // tier2 (24.75 MiB): all bf16, dt aliases xc (xc dead after conv_silu)
    unsigned short* xc = (unsigned short*)d_ws;
    unsigned short* z  = xc + NE;
    unsigned short* xs = z + NE;
    float* proj = (float*)(xs + NE);
    run_pipeline<unsigned short, unsigned short>(
        x, W_in, W_conv, b_conv, W_xp, W_dt, b_dt, A_log,
        D_par, W_out, out, xc, z, xs, /*dtb=*/xc, proj, stream);
  }
}

// Round 8
// 233.418 us; speedup vs baseline: 5.9466x; 1.4237x over previous
//
#include <hip/hip_runtime.h>
#include <math.h>

#define D_MODEL   1024
#define D_INNER_  2048
#define D_STATE_  16
#define DT_RANK_  64
#define SEQ       1024
#define NTOK      2048          // B * L
#define XPROJ_N   96            // dt_rank + 2*d_state
#define NC        16            // scan chunks per sequence
#define TC        64            // timesteps per chunk (NC*TC == SEQ)
#define SPLITK    8             // K-splits for the x-projection
#define KCHUNK    (D_INNER_ / SPLITK)   // 256

typedef __attribute__((ext_vector_type(8))) short s16x8;
typedef __attribute__((ext_vector_type(4))) float f32x4;

// ---------------- bf16 helpers ---------------------------------------------
__device__ __forceinline__ float bf2f(unsigned short u) {
  return __uint_as_float(((unsigned int)u) << 16);
}
__device__ __forceinline__ unsigned short f2bf(float f) {
  unsigned int x = __float_as_uint(f);
  x += 0x7FFF + ((x >> 16) & 1);          // round-to-nearest-even
  return (unsigned short)(x >> 16);
}

template <typename T> struct VIO;
template <> struct VIO<float> {
  static __device__ __forceinline__ float4 ld4(const float* p) { return *(const float4*)p; }
  static __device__ __forceinline__ float ld(const float* p) { return *p; }
  static __device__ __forceinline__ void st(float* p, float v) { *p = v; }
};
template <> struct VIO<unsigned short> {
  static __device__ __forceinline__ float4 ld4(const unsigned short* p) {
    ushort4 u = *(const ushort4*)p;
    return make_float4(bf2f(u.x), bf2f(u.y), bf2f(u.z), bf2f(u.w));
  }
  static __device__ __forceinline__ float ld(const unsigned short* p) { return bf2f(*p); }
  static __device__ __forceinline__ void st(unsigned short* p, float v) { *p = f2bf(v); }
};

// ---------------------------------------------------------------------------
// fp32 -> bf16 bulk convert (8 elems/thread).  n % 8 == 0.
// ---------------------------------------------------------------------------
__global__ __launch_bounds__(256) void f32_to_bf16(
    const float* __restrict__ s, unsigned short* __restrict__ d, int n)
{
  const int i = (blockIdx.x * 256 + threadIdx.x) * 8;
  if (i >= n) return;
  float4 a = *(const float4*)(s + i);
  float4 b = *(const float4*)(s + i + 4);
  s16x8 v;
  v[0] = (short)f2bf(a.x); v[1] = (short)f2bf(a.y);
  v[2] = (short)f2bf(a.z); v[3] = (short)f2bf(a.w);
  v[4] = (short)f2bf(b.x); v[5] = (short)f2bf(b.y);
  v[6] = (short)f2bf(b.z); v[7] = (short)f2bf(b.w);
  *(s16x8*)(d + i) = v;
}

// ---------------------------------------------------------------------------
// bf16 MFMA NT GEMM, templated tile: C[M][N] = A[M][K] * B[N][K]^T.
// 4 waves in 2x2; wave subtile (BM/2)x(BN/2) = FIxFJ frags of 16x16x32.
// 2-phase pipeline: next tile's global loads issued before the MFMA phase.
// SPLIT: N = 2*ldc, columns < ldc -> C0, else -> C1 (in-proj xz split).
// Requires BM*BK == BN*BK == 4096 (one s16x8 pair staged per thread/matrix).
// ---------------------------------------------------------------------------
template <int BM, int BN, int BK, bool SPLIT, typename TCout>
__global__ __launch_bounds__(256) void gemm_bf16_nt(
    const unsigned short* __restrict__ A, const unsigned short* __restrict__ B,
    TCout* __restrict__ C0, TCout* __restrict__ C1,
    int M, int N, int K, int ldc)
{
  static_assert(BM * BK == 4096 && BN * BK == 4096, "staging map");
  constexpr int PITCH = BK + 8;                  // shorts; +16B pad
  constexpr int FI = BM / 32, FJ = BN / 32;      // frags per wave
  constexpr int TPR = BK / 16;                   // staging threads per row
  __shared__ __align__(16) short As[BM * PITCH];
  __shared__ __align__(16) short Bs[BN * PITCH];

  const int ntiles = N / BN;
  const int mt = blockIdx.x / ntiles, nt = blockIdx.x % ntiles;
  const int m0 = mt * BM, n0 = nt * BN;
  const int tid = threadIdx.x;
  const int lane = tid & 63;
  const int w = tid >> 6;
  const int wm = (w >> 1) * (BM / 2), wn = (w & 1) * (BN / 2);
  const int lrow = lane & 15;
  const int lk8 = (lane >> 4) << 3;

  const int arow = tid / TPR;                    // 0..BM-1
  const int koff = (tid % TPR) * 16;
  const unsigned short* pa = A + (size_t)(m0 + arow) * K + koff;
  const unsigned short* pb = B + (size_t)(n0 + arow) * K + koff;

  f32x4 acc[FI][FJ];
#pragma unroll
  for (int i = 0; i < FI; ++i)
#pragma unroll
    for (int j = 0; j < FJ; ++j) acc[i][j] = (f32x4){0.f, 0.f, 0.f, 0.f};

  s16x8 ra0 = *(const s16x8*)pa, ra1 = *(const s16x8*)(pa + 8);
  s16x8 rb0 = *(const s16x8*)pb, rb1 = *(const s16x8*)(pb + 8);

  for (int k0 = 0; k0 < K; k0 += BK) {
    __syncthreads();                             // previous compute done
    *(s16x8*)&As[arow * PITCH + koff]     = ra0;
    *(s16x8*)&As[arow * PITCH + koff + 8] = ra1;
    *(s16x8*)&Bs[arow * PITCH + koff]     = rb0;
    *(s16x8*)&Bs[arow * PITCH + koff + 8] = rb1;
    __syncthreads();
    if (k0 + BK < K) {                           // prefetch next tile (flies
      pa += BK; pb += BK;                        //  under the MFMA phase)
      ra0 = *(const s16x8*)pa; ra1 = *(const s16x8*)(pa + 8);
      rb0 = *(const s16x8*)pb; rb1 = *(const s16x8*)(pb + 8);
    }
    s16x8 af[FI][BK / 32], bfr[FJ][BK / 32];
#pragma unroll
    for (int ks = 0; ks < BK / 32; ++ks) {
#pragma unroll
      for (int i = 0; i < FI; ++i)
        af[i][ks] = *(const s16x8*)&As[(wm + i * 16 + lrow) * PITCH + ks * 32 + lk8];
#pragma unroll
      for (int j = 0; j < FJ; ++j)
        bfr[j][ks] = *(const s16x8*)&Bs[(wn + j * 16 + lrow) * PITCH + ks * 32 + lk8];
    }
#pragma unroll
    for (int ks = 0; ks < BK / 32; ++ks)
#pragma unroll
      for (int i = 0; i < FI; ++i)
#pragma unroll
        for (int j = 0; j < FJ; ++j)
          acc[i][j] = __builtin_amdgcn_mfma_f32_16x16x32_bf16(
              af[i][ks], bfr[j][ks], acc[i][j], 0, 0, 0);
  }

  // epilogue: C/D layout col = lane&15 (B idx), row = (lane>>4)*4+reg (A idx)
  const int crow0 = m0 + wm + (lane >> 4) * 4;
  TCout* dst = C0;
  int ccol0 = n0 + wn + lrow;
  if (SPLIT && n0 >= ldc) { dst = C1; ccol0 -= ldc; }
#pragma unroll
  for (int i = 0; i < FI; ++i)
#pragma unroll
    for (int j = 0; j < FJ; ++j)
#pragma unroll
      for (int r = 0; r < 4; ++r)
        VIO<TCout>::st(&dst[(size_t)(crow0 + i * 16 + r) * ldc + ccol0 + j * 16],
                       acc[i][j][r]);
}

// ---------------------------------------------------------------------------
// Causal depthwise conv (k=4, left pad 3) + bias + silu.  (unchanged)
// ---------------------------------------------------------------------------
template <typename TIn, typename TOut>
__global__ __launch_bounds__(256) void conv_silu(
    const TIn* __restrict__ xc, const float* __restrict__ Wc,
    const float* __restrict__ bc, TOut* __restrict__ xs)
{
  const int idx = blockIdx.x * 256 + threadIdx.x;   // NTOK * D_INNER
  const int d = idx & (D_INNER_ - 1);
  const int t = idx >> 11;                          // token = b*L + l
  const int l = t & (SEQ - 1);
  const float4 w = *(const float4*)(Wc + d * 4);    // W_conv[d][0][0..3]
  const TIn* col = xc + (size_t)t * D_INNER_ + d;
  float acc = bc[d] + VIO<TIn>::ld(col) * w.w;
  if (l >= 1) acc += VIO<TIn>::ld(col - D_INNER_)     * w.z;
  if (l >= 2) acc += VIO<TIn>::ld(col - 2 * D_INNER_) * w.y;
  if (l >= 3) acc += VIO<TIn>::ld(col - 3 * D_INNER_) * w.x;
  VIO<TOut>::st(&xs[idx], acc / (1.f + __expf(-acc))); // silu
}

// ---------------------------------------------------------------------------
// x-projection, split-K.  (unchanged)
// ---------------------------------------------------------------------------
template <typename T>
__global__ __launch_bounds__(256) void gemm_proj_splitk(
    const T* __restrict__ xs, const float* __restrict__ Wx,
    float* __restrict__ partial)
{
  __shared__ float As[16][68];
  __shared__ float Ws[96][68];
  const int mtile = blockIdx.x & 127;
  const int s = blockIdx.x >> 7;            // K-split 0..7
  const int m0 = mtile * 16;
  const int kbase = s * KCHUNK;
  const int tid = threadIdx.x;
  const int r = tid & 15;           // compute row
  const int cg = tid >> 4;          // col group 0..15, cols cg*6 + j
  float acc[6] = {0.f, 0.f, 0.f, 0.f, 0.f, 0.f};
  const int ar = tid >> 4, ak = (tid & 15) * 4;     // A stage mapping

  for (int k0 = kbase; k0 < kbase + KCHUNK; k0 += 64) {
    float4 av = VIO<T>::ld4(xs + (size_t)(m0 + ar) * D_INNER_ + k0 + ak);
    float4 wv[6];
#pragma unroll
    for (int q = 0; q < 6; ++q) {
      int g = tid + 256 * q;        // f4 index into 96x64 tile
      int wr = g >> 4, wk = (g & 15) * 4;
      wv[q] = *(const float4*)(Wx + (size_t)wr * D_INNER_ + k0 + wk);
    }
    __syncthreads();
    *(float4*)&As[ar][ak] = av;
#pragma unroll
    for (int q = 0; q < 6; ++q) {
      int g = tid + 256 * q;
      int wr = g >> 4, wk = (g & 15) * 4;
      *(float4*)&Ws[wr][wk] = wv[q];
    }
    __syncthreads();
    for (int kk = 0; kk < 64; kk += 4) {
      float4 a = *(const float4*)&As[r][kk];
#pragma unroll
      for (int j = 0; j < 6; ++j) {
        float4 w = *(const float4*)&Ws[cg * 6 + j][kk];
        acc[j] += a.x * w.x + a.y * w.y + a.z * w.z + a.w * w.w;
      }
    }
  }
#pragma unroll
  for (int j = 0; j < 6; ++j)
    partial[((size_t)s * NTOK + m0 + r) * XPROJ_N + cg * 6 + j] = acc[j];
}

__global__ __launch_bounds__(256) void proj_reduce(
    const float* __restrict__ partial, float* __restrict__ proj)
{
  const int gid = blockIdx.x * 256 + threadIdx.x;   // NTOK*XPROJ_N = 196608
  float s = 0.f;
#pragma unroll
  for (int i = 0; i < SPLITK; ++i)
    s += partial[(size_t)i * NTOK * XPROJ_N + gid];
  proj[gid] = s;
}

// ---------------------------------------------------------------------------
// dt GEMM (K=64) + bias + stable softplus.  (unchanged)
// ---------------------------------------------------------------------------
template <typename T>
__global__ __launch_bounds__(256) void gemm_dt_softplus(
    const float* __restrict__ proj, const float* __restrict__ Wdt,
    const float* __restrict__ bdt, T* __restrict__ dt)
{
  __shared__ float As[64][68];
  __shared__ float Bs[64][68];
  const int ntb = blockIdx.x & 31;          // D_INNER/64 = 32
  const int mt = blockIdx.x >> 5;
  const int m0 = mt << 6, n0 = ntb << 6;
  const int tid = threadIdx.x;
  const int tr = tid >> 4, tc = tid & 15;

#pragma unroll
  for (int q = 0; q < 4; ++q) {
    int f = tid + 256 * q;                  // f4 index into 64x64 tile
    int row = f >> 4, k4 = (f & 15) * 4;
    *(float4*)&As[row][k4] = *(const float4*)(proj + (size_t)(m0 + row) * XPROJ_N + k4);
    *(float4*)&Bs[row][k4] = *(const float4*)(Wdt + (size_t)(n0 + row) * DT_RANK_ + k4);
  }
  __syncthreads();

  float acc[4][4] = {{0.f, 0.f, 0.f, 0.f}, {0.f, 0.f, 0.f, 0.f},
                     {0.f, 0.f, 0.f, 0.f}, {0.f, 0.f, 0.f, 0.f}};
  for (int kk = 0; kk < 64; kk += 4) {
    float4 a[4], b[4];
#pragma unroll
    for (int i = 0; i < 4; ++i) a[i] = *(const float4*)&As[tr * 4 + i][kk];
#pragma unroll
    for (int j = 0; j < 4; ++j) b[j] = *(const float4*)&Bs[tc * 4 + j][kk];
#pragma unroll
    for (int i = 0; i < 4; ++i)
#pragma unroll
      for (int j = 0; j < 4; ++j)
        acc[i][j] += a[i].x * b[j].x + a[i].y * b[j].y +
                     a[i].z * b[j].z + a[i].w * b[j].w;
  }
#pragma unroll
  for (int i = 0; i < 4; ++i) {
#pragma unroll
    for (int j = 0; j < 4; ++j) {
      float z = acc[i][j] + bdt[n0 + tc * 4 + j];
      float sp = fmaxf(z, 0.f) + log1pf(__expf(-fabsf(z)));   // stable softplus
      VIO<T>::st(dt + (size_t)(m0 + tr * 4 + i) * D_INNER_ + n0 + tc * 4 + j, sp);
    }
  }
}

// ---------------------------------------------------------------------------
// Register-state chunked scan (3 passes).  (unchanged from round 7)
// ---------------------------------------------------------------------------
template <typename TD, typename TX>
__global__ __launch_bounds__(256) void scan2_reduce(
    const float* __restrict__ proj, const TD* __restrict__ dt,
    const TX* __restrict__ xs, const float* __restrict__ A_log,
    float* __restrict__ q, float* __restrict__ sdt)
{
  __shared__ float Bsh[TC][16];
  const int tid = threadIdx.x;
  const int b = blockIdx.x >> 7;
  const int c = (blockIdx.x >> 3) & (NC - 1);
  const int d = ((blockIdx.x & 7) << 8) + tid;
  const size_t tok0 = (size_t)b * SEQ + (size_t)c * TC;
  { // stage B rows: 64 x 16 floats, 1 float4 per thread
    const int e = tid * 4, t = e >> 4, col = e & 15;
    *(float4*)&Bsh[t][col] = *(const float4*)&proj[(tok0 + t) * XPROJ_N + DT_RANK_ + col];
  }
  float An[D_STATE_];
#pragma unroll
  for (int n = 0; n < D_STATE_; ++n) An[n] = -__expf(A_log[d * D_STATE_ + n]);
  __syncthreads();

  float h[D_STATE_];
#pragma unroll
  for (int n = 0; n < D_STATE_; ++n) h[n] = 0.f;
  float s = 0.f;
  for (int t = 0; t < TC; ++t) {
    const size_t tt = tok0 + t;
    const float dtv = VIO<TD>::ld(&dt[tt * D_INNER_ + d]);
    const float xsv = VIO<TX>::ld(&xs[tt * D_INNER_ + d]);
    s += dtv;
    const float dx = dtv * xsv;
    float Bv[D_STATE_];
#pragma unroll
    for (int k = 0; k < 4; ++k)
      *(float4*)&Bv[4 * k] = *(const float4*)&Bsh[t][4 * k];
#pragma unroll
    for (int n = 0; n < D_STATE_; ++n)
      h[n] = __expf(dtv * An[n]) * h[n] + dx * Bv[n];
  }
  const size_t idx = (size_t)(b * NC + c) * D_INNER_ + d;
#pragma unroll
  for (int k = 0; k < 4; ++k)
    *(float4*)&q[idx * D_STATE_ + 4 * k] =
        make_float4(h[4 * k], h[4 * k + 1], h[4 * k + 2], h[4 * k + 3]);
  sdt[idx] = s;
}

__global__ __launch_bounds__(256) void scan2_mid(
    float* __restrict__ q, const float* __restrict__ sdt,
    const float* __restrict__ A_log)
{
  const int gid = blockIdx.x * 256 + threadIdx.x;   // (b*D_INNER+d)*16+n
  const int n = gid & 15;
  const int d = (gid >> 4) & (D_INNER_ - 1);
  const int b = gid >> 15;
  const float An = -__expf(A_log[d * D_STATE_ + n]);
  float h = 0.f;
#pragma unroll
  for (int c = 0; c < NC; ++c) {
    const size_t idx = (size_t)(b * NC + c) * D_INNER_ + d;
    const float P = __expf(An * sdt[idx]);
    const float qq = q[idx * D_STATE_ + n];
    q[idx * D_STATE_ + n] = h;        // h at chunk start
    h = P * h + qq;
  }
}

template <typename TD, typename TX>
__global__ __launch_bounds__(256) void scan2_apply(
    const float* __restrict__ proj, const TD* __restrict__ dt,
    const TX* __restrict__ xs, unsigned short* __restrict__ zy,
    const float* __restrict__ A_log, const float* __restrict__ D_par,
    const float* __restrict__ hstart)
{
  __shared__ float BC[TC][32];      // [t][0..15] = B, [t][16..31] = C
  const int tid = threadIdx.x;
  const int b = blockIdx.x >> 7;
  const int c = (blockIdx.x >> 3) & (NC - 1);
  const int d = ((blockIdx.x & 7) << 8) + tid;
  const size_t tok0 = (size_t)b * SEQ + (size_t)c * TC;
  { // stage B+C: 64 x 32 floats, 2 float4 per thread
    const int e = tid * 8, t = e >> 5, col = e & 31;
    const float* src = &proj[(tok0 + t) * XPROJ_N + DT_RANK_ + col];
    *(float4*)&BC[t][col]     = *(const float4*)src;
    *(float4*)&BC[t][col + 4] = *(const float4*)(src + 4);
  }
  float An[D_STATE_];
#pragma unroll
  for (int n = 0; n < D_STATE_; ++n) An[n] = -__expf(A_log[d * D_STATE_ + n]);
  const float Dd = D_par[d];
  const size_t idx = (size_t)(b * NC + c) * D_INNER_ + d;
  float h[D_STATE_];
#pragma unroll
  for (int k = 0; k < 4; ++k) {
    float4 v = *(const float4*)&hstart[idx * D_STATE_ + 4 * k];
    h[4 * k] = v.x; h[4 * k + 1] = v.y; h[4 * k + 2] = v.z; h[4 * k + 3] = v.w;
  }
  __syncthreads();

  for (int t = 0; t < TC; ++t) {
    const size_t tt = tok0 + t;
    const float dtv = VIO<TD>::ld(&dt[tt * D_INNER_ + d]);
    const float xsv = VIO<TX>::ld(&xs[tt * D_INNER_ + d]);
    const float zv  = bf2f(zy[tt * D_INNER_ + d]);
    const float dx = dtv * xsv;
    float Bv[D_STATE_], Cv[D_STATE_];
#pragma unroll
    for (int k = 0; k < 4; ++k) {
      *(float4*)&Bv[4 * k] = *(const float4*)&BC[t][4 * k];
      *(float4*)&Cv[4 * k] = *(const float4*)&BC[t][16 + 4 * k];
    }
    float y = 0.f;
#pragma unroll
    for (int n = 0; n < D_STATE_; ++n) {
      h[n] = __expf(dtv * An[n]) * h[n] + dx * Bv[n];
      y += h[n] * Cv[n];
    }
    const float g = zv / (1.f + __expf(-zv));      // silu(z)
    zy[tt * D_INNER_ + d] = f2bf((y + Dd * xsv) * g);
  }
}

// ---------------------------------------------------------------------------
// TD = dt storage type, TX = xs storage type.  xc/z/zy always bf16 (ushort).
// Dead-window aliases: xbf -> xs region (xs written later by conv);
// winbf -> d_out (free until split-K partials); wobf -> xs region (xs dead
// after scan2_apply).  All stream-ordered.
template <typename TD, typename TX>
static void run_pipeline(const float* x, const float* W_in, const float* W_conv,
                         const float* b_conv, const float* W_xp, const float* W_dt,
                         const float* b_dt, const float* A_log, const float* D_par,
                         const float* W_out, float* out,
                         unsigned short* xc, unsigned short* z, TX* xs,
                         TD* dtb, float* proj, hipStream_t stream)
{
  unsigned short* zy = z;   // scan overwrites z with gated y in place
  float* partial = out;                                       // step 3 scratch
  float* qbuf = out;                                          // step 5 scratch
  float* sdt  = out + (size_t)2 * NC * D_INNER_ * D_STATE_;   // + 1M floats
  unsigned short* xbf   = (unsigned short*)xs;                // 4 MiB
  unsigned short* winbf = (unsigned short*)out;               // 8 MiB exactly
  unsigned short* wobf  = (unsigned short*)xs;                // 4 MiB (late)

  // 0) pre-convert x and W_in to bf16
  f32_to_bf16<<<dim3(NTOK * D_MODEL / 2048), dim3(256), 0, stream>>>(
      x, xbf, NTOK * D_MODEL);
  f32_to_bf16<<<dim3(2 * D_INNER_ * D_MODEL / 2048), dim3(256), 0, stream>>>(
      W_in, winbf, 2 * D_INNER_ * D_MODEL);
  // 1) fused in-proj: [xc | z] = xbf @ winbf^T   (N=4096, split epilogue)
  gemm_bf16_nt<128, 128, 32, true, unsigned short>
      <<<dim3((NTOK / 128) * (2 * D_INNER_ / 128)), dim3(256), 0, stream>>>(
      xbf, winbf, xc, z, NTOK, 2 * D_INNER_, D_MODEL, D_INNER_);
  // 2) xs = silu(causal_dwconv(xc) + b_conv)
  conv_silu<unsigned short, TX><<<dim3(NTOK * D_INNER_ / 256), dim3(256), 0, stream>>>(
      xc, W_conv, b_conv, xs);
  // 3) proj = xs @ W_xproj^T   (split-K x8 into d_out, then reduce)
  gemm_proj_splitk<TX><<<dim3(SPLITK * (NTOK / 16)), dim3(256), 0, stream>>>(
      xs, W_xp, partial);
  proj_reduce<<<dim3(NTOK * XPROJ_N / 256), dim3(256), 0, stream>>>(partial, proj);
  // 4) dt = softplus(dt_low @ W_dt^T + b_dt)
  gemm_dt_softplus<TD><<<dim3((NTOK / 64) * (D_INNER_ / 64)), dim3(256), 0, stream>>>(
      proj, W_dt, b_dt, dtb);
  // 5) register-state chunked scan + gating  (z -> y*silu(z) in place)
  scan2_reduce<TD, TX><<<dim3(2 * NC * (D_INNER_ / 256)), dim3(256), 0, stream>>>(
      proj, dtb, xs, A_log, qbuf, sdt);
  scan2_mid<<<dim3(2 * D_INNER_ * D_STATE_ / 256), dim3(256), 0, stream>>>(
      qbuf, sdt, A_log);
  scan2_apply<TD, TX><<<dim3(2 * NC * (D_INNER_ / 256)), dim3(256), 0, stream>>>(
      proj, dtb, xs, zy, A_log, D_par, qbuf);
  // 5.5) convert W_out -> bf16 (xs region is dead now)
  f32_to_bf16<<<dim3(D_MODEL * D_INNER_ / 2048), dim3(256), 0, stream>>>(
      W_out, wobf, D_MODEL * D_INNER_);
  // 6) out = zy @ wobf^T
  gemm_bf16_nt<64, 64, 64, false, float>
      <<<dim3((NTOK / 64) * (D_MODEL / 64)), dim3(256), 0, stream>>>(
      zy, wobf, out, nullptr, NTOK, D_MODEL, D_INNER_, D_MODEL);
}

extern "C" void kernel_launch(void* const* d_in, const int* in_sizes, int n_in,
                              void* d_out, int out_size, void* d_ws, size_t ws_size,
                              hipStream_t stream)
{
  const float* x      = (const float*)d_in[0];
  const float* W_in   = (const float*)d_in[1];
  const float* W_conv = (const float*)d_in[2];
  const float* b_conv = (const float*)d_in[3];
  const float* W_xp   = (const float*)d_in[4];
  const float* W_dt   = (const float*)d_in[5];
  const float* b_dt   = (const float*)d_in[6];
  const float* A_log  = (const float*)d_in[7];
  const float* D_par  = (const float*)d_in[8];
  const float* W_out  = (const float*)d_in[9];
  float* out = (float*)d_out;

  const size_t NE = (size_t)NTOK * D_INNER_;          // 4,194,304 elements
  // tier1: xc(bf16) z(bf16) xs(f32) dt(f32) proj(f32) = 48.75 MiB
  const size_t need_t1 = NE * 2 + NE * 2 + NE * 4 + NE * 4
                       + (size_t)NTOK * XPROJ_N * 4;

  if (ws_size >= need_t1) {
    unsigned short* xc = (unsigned short*)d_ws;
    unsigned short* z  = xc + NE;
    float* xs   = (float*)(z + NE);
    float* dtb  = xs + NE;
    float* proj = dtb + NE;
    run_pipeline<float, float>(x, W_in, W_conv, b_conv, W_xp, W_dt, b_dt, A_log,
                               D_par, W_out, out, xc, z, xs, dtb, proj, stream);
  } else {
    // tier2 (24.75 MiB): all bf16, dt aliases xc (xc dead after conv_silu)
    unsigned short* xc = (unsigned short*)d_ws;
    unsigned short* z  = xc + NE;
    unsigned short* xs = z + NE;
    float* proj = (float*)(xs + NE);
    run_pipeline<unsigned short, unsigned short>(
        x, W_in, W_conv, b_conv, W_xp, W_dt, b_dt, A_log,
        D_par, W_out, out, xc, z, xs, /*dtb=*/xc, proj, stream);
  }
}

// Round 9
// 193.408 us; speedup vs baseline: 7.1768x; 1.2069x over previous
//
#include <hip/hip_runtime.h>
#include <math.h>

#define D_MODEL   1024
#define D_INNER_  2048
#define D_STATE_  16
#define DT_RANK_  64
#define SEQ       1024
#define NTOK      2048          // B * L
#define XPROJ_N   96            // dt_rank + 2*d_state
#define SPLITK    8             // K-splits for the x-projection
#define KCHUNK    (D_INNER_ / SPLITK)   // 256

typedef __attribute__((ext_vector_type(8))) short s16x8;
typedef __attribute__((ext_vector_type(4))) float f32x4;

// ---------------- bf16 helpers ---------------------------------------------
__device__ __forceinline__ float bf2f(unsigned short u) {
  return __uint_as_float(((unsigned int)u) << 16);
}
__device__ __forceinline__ unsigned short f2bf(float f) {
  unsigned int x = __float_as_uint(f);
  x += 0x7FFF + ((x >> 16) & 1);          // round-to-nearest-even
  return (unsigned short)(x >> 16);
}

template <typename T> struct VIO;
template <> struct VIO<float> {
  static __device__ __forceinline__ float4 ld4(const float* p) { return *(const float4*)p; }
  static __device__ __forceinline__ float ld(const float* p) { return *p; }
  static __device__ __forceinline__ void st(float* p, float v) { *p = v; }
};
template <> struct VIO<unsigned short> {
  static __device__ __forceinline__ float4 ld4(const unsigned short* p) {
    ushort4 u = *(const ushort4*)p;
    return make_float4(bf2f(u.x), bf2f(u.y), bf2f(u.z), bf2f(u.w));
  }
  static __device__ __forceinline__ float ld(const unsigned short* p) { return bf2f(*p); }
  static __device__ __forceinline__ void st(unsigned short* p, float v) { *p = f2bf(v); }
};

// ---------------------------------------------------------------------------
// fp32 -> bf16 bulk convert (8 elems/thread).  n % 8 == 0.
// ---------------------------------------------------------------------------
__global__ __launch_bounds__(256) void f32_to_bf16(
    const float* __restrict__ s, unsigned short* __restrict__ d, int n)
{
  const int i = (blockIdx.x * 256 + threadIdx.x) * 8;
  if (i >= n) return;
  float4 a = *(const float4*)(s + i);
  float4 b = *(const float4*)(s + i + 4);
  s16x8 v;
  v[0] = (short)f2bf(a.x); v[1] = (short)f2bf(a.y);
  v[2] = (short)f2bf(a.z); v[3] = (short)f2bf(a.w);
  v[4] = (short)f2bf(b.x); v[5] = (short)f2bf(b.y);
  v[6] = (short)f2bf(b.z); v[7] = (short)f2bf(b.w);
  *(s16x8*)(d + i) = v;
}

// ---------------------------------------------------------------------------
// bf16 MFMA NT GEMM, templated tile.  (unchanged from round 8)
// ---------------------------------------------------------------------------
template <int BM, int BN, int BK, bool SPLIT, typename TCout>
__global__ __launch_bounds__(256) void gemm_bf16_nt(
    const unsigned short* __restrict__ A, const unsigned short* __restrict__ B,
    TCout* __restrict__ C0, TCout* __restrict__ C1,
    int M, int N, int K, int ldc)
{
  static_assert(BM * BK == 4096 && BN * BK == 4096, "staging map");
  constexpr int PITCH = BK + 8;                  // shorts; +16B pad
  constexpr int FI = BM / 32, FJ = BN / 32;      // frags per wave
  constexpr int TPR = BK / 16;                   // staging threads per row
  __shared__ __align__(16) short As[BM * PITCH];
  __shared__ __align__(16) short Bs[BN * PITCH];

  const int ntiles = N / BN;
  const int mt = blockIdx.x / ntiles, nt = blockIdx.x % ntiles;
  const int m0 = mt * BM, n0 = nt * BN;
  const int tid = threadIdx.x;
  const int lane = tid & 63;
  const int w = tid >> 6;
  const int wm = (w >> 1) * (BM / 2), wn = (w & 1) * (BN / 2);
  const int lrow = lane & 15;
  const int lk8 = (lane >> 4) << 3;

  const int arow = tid / TPR;                    // 0..BM-1
  const int koff = (tid % TPR) * 16;
  const unsigned short* pa = A + (size_t)(m0 + arow) * K + koff;
  const unsigned short* pb = B + (size_t)(n0 + arow) * K + koff;

  f32x4 acc[FI][FJ];
#pragma unroll
  for (int i = 0; i < FI; ++i)
#pragma unroll
    for (int j = 0; j < FJ; ++j) acc[i][j] = (f32x4){0.f, 0.f, 0.f, 0.f};

  s16x8 ra0 = *(const s16x8*)pa, ra1 = *(const s16x8*)(pa + 8);
  s16x8 rb0 = *(const s16x8*)pb, rb1 = *(const s16x8*)(pb + 8);

  for (int k0 = 0; k0 < K; k0 += BK) {
    __syncthreads();                             // previous compute done
    *(s16x8*)&As[arow * PITCH + koff]     = ra0;
    *(s16x8*)&As[arow * PITCH + koff + 8] = ra1;
    *(s16x8*)&Bs[arow * PITCH + koff]     = rb0;
    *(s16x8*)&Bs[arow * PITCH + koff + 8] = rb1;
    __syncthreads();
    if (k0 + BK < K) {                           // prefetch next tile (flies
      pa += BK; pb += BK;                        //  under the MFMA phase)
      ra0 = *(const s16x8*)pa; ra1 = *(const s16x8*)(pa + 8);
      rb0 = *(const s16x8*)pb; rb1 = *(const s16x8*)(pb + 8);
    }
    s16x8 af[FI][BK / 32], bfr[FJ][BK / 32];
#pragma unroll
    for (int ks = 0; ks < BK / 32; ++ks) {
#pragma unroll
      for (int i = 0; i < FI; ++i)
        af[i][ks] = *(const s16x8*)&As[(wm + i * 16 + lrow) * PITCH + ks * 32 + lk8];
#pragma unroll
      for (int j = 0; j < FJ; ++j)
        bfr[j][ks] = *(const s16x8*)&Bs[(wn + j * 16 + lrow) * PITCH + ks * 32 + lk8];
    }
#pragma unroll
    for (int ks = 0; ks < BK / 32; ++ks)
#pragma unroll
      for (int i = 0; i < FI; ++i)
#pragma unroll
        for (int j = 0; j < FJ; ++j)
          acc[i][j] = __builtin_amdgcn_mfma_f32_16x16x32_bf16(
              af[i][ks], bfr[j][ks], acc[i][j], 0, 0, 0);
  }

  // epilogue: C/D layout col = lane&15 (B idx), row = (lane>>4)*4+reg (A idx)
  const int crow0 = m0 + wm + (lane >> 4) * 4;
  TCout* dst = C0;
  int ccol0 = n0 + wn + lrow;
  if (SPLIT && n0 >= ldc) { dst = C1; ccol0 -= ldc; }
#pragma unroll
  for (int i = 0; i < FI; ++i)
#pragma unroll
    for (int j = 0; j < FJ; ++j)
#pragma unroll
      for (int r = 0; r < 4; ++r)
        VIO<TCout>::st(&dst[(size_t)(crow0 + i * 16 + r) * ldc + ccol0 + j * 16],
                       acc[i][j][r]);
}

// ---------------------------------------------------------------------------
// Causal depthwise conv (k=4, left pad 3) + bias + silu.  (unchanged)
// ---------------------------------------------------------------------------
template <typename TIn, typename TOut>
__global__ __launch_bounds__(256) void conv_silu(
    const TIn* __restrict__ xc, const float* __restrict__ Wc,
    const float* __restrict__ bc, TOut* __restrict__ xs)
{
  const int idx = blockIdx.x * 256 + threadIdx.x;   // NTOK * D_INNER
  const int d = idx & (D_INNER_ - 1);
  const int t = idx >> 11;                          // token = b*L + l
  const int l = t & (SEQ - 1);
  const float4 w = *(const float4*)(Wc + d * 4);    // W_conv[d][0][0..3]
  const TIn* col = xc + (size_t)t * D_INNER_ + d;
  float acc = bc[d] + VIO<TIn>::ld(col) * w.w;
  if (l >= 1) acc += VIO<TIn>::ld(col - D_INNER_)     * w.z;
  if (l >= 2) acc += VIO<TIn>::ld(col - 2 * D_INNER_) * w.y;
  if (l >= 3) acc += VIO<TIn>::ld(col - 3 * D_INNER_) * w.x;
  VIO<TOut>::st(&xs[idx], acc / (1.f + __expf(-acc))); // silu
}

// ---------------------------------------------------------------------------
// x-projection, split-K.  (unchanged)
// ---------------------------------------------------------------------------
template <typename T>
__global__ __launch_bounds__(256) void gemm_proj_splitk(
    const T* __restrict__ xs, const float* __restrict__ Wx,
    float* __restrict__ partial)
{
  __shared__ float As[16][68];
  __shared__ float Ws[96][68];
  const int mtile = blockIdx.x & 127;
  const int s = blockIdx.x >> 7;            // K-split 0..7
  const int m0 = mtile * 16;
  const int kbase = s * KCHUNK;
  const int tid = threadIdx.x;
  const int r = tid & 15;           // compute row
  const int cg = tid >> 4;          // col group 0..15, cols cg*6 + j
  float acc[6] = {0.f, 0.f, 0.f, 0.f, 0.f, 0.f};
  const int ar = tid >> 4, ak = (tid & 15) * 4;     // A stage mapping

  for (int k0 = kbase; k0 < kbase + KCHUNK; k0 += 64) {
    float4 av = VIO<T>::ld4(xs + (size_t)(m0 + ar) * D_INNER_ + k0 + ak);
    float4 wv[6];
#pragma unroll
    for (int q = 0; q < 6; ++q) {
      int g = tid + 256 * q;        // f4 index into 96x64 tile
      int wr = g >> 4, wk = (g & 15) * 4;
      wv[q] = *(const float4*)(Wx + (size_t)wr * D_INNER_ + k0 + wk);
    }
    __syncthreads();
    *(float4*)&As[ar][ak] = av;
#pragma unroll
    for (int q = 0; q < 6; ++q) {
      int g = tid + 256 * q;
      int wr = g >> 4, wk = (g & 15) * 4;
      *(float4*)&Ws[wr][wk] = wv[q];
    }
    __syncthreads();
    for (int kk = 0; kk < 64; kk += 4) {
      float4 a = *(const float4*)&As[r][kk];
#pragma unroll
      for (int j = 0; j < 6; ++j) {
        float4 w = *(const float4*)&Ws[cg * 6 + j][kk];
        acc[j] += a.x * w.x + a.y * w.y + a.z * w.z + a.w * w.w;
      }
    }
  }
#pragma unroll
  for (int j = 0; j < 6; ++j)
    partial[((size_t)s * NTOK + m0 + r) * XPROJ_N + cg * 6 + j] = acc[j];
}

__global__ __launch_bounds__(256) void proj_reduce(
    const float* __restrict__ partial, float* __restrict__ proj)
{
  const int gid = blockIdx.x * 256 + threadIdx.x;   // NTOK*XPROJ_N = 196608
  float s = 0.f;
#pragma unroll
  for (int i = 0; i < SPLITK; ++i)
    s += partial[(size_t)i * NTOK * XPROJ_N + gid];
  proj[gid] = s;
}

// ---------------------------------------------------------------------------
// dt GEMM (K=64) + bias + stable softplus.  (unchanged)
// ---------------------------------------------------------------------------
template <typename T>
__global__ __launch_bounds__(256) void gemm_dt_softplus(
    const float* __restrict__ proj, const float* __restrict__ Wdt,
    const float* __restrict__ bdt, T* __restrict__ dt)
{
  __shared__ float As[64][68];
  __shared__ float Bs[64][68];
  const int ntb = blockIdx.x & 31;          // D_INNER/64 = 32
  const int mt = blockIdx.x >> 5;
  const int m0 = mt << 6, n0 = ntb << 6;
  const int tid = threadIdx.x;
  const int tr = tid >> 4, tc = tid & 15;

#pragma unroll
  for (int q = 0; q < 4; ++q) {
    int f = tid + 256 * q;                  // f4 index into 64x64 tile
    int row = f >> 4, k4 = (f & 15) * 4;
    *(float4*)&As[row][k4] = *(const float4*)(proj + (size_t)(m0 + row) * XPROJ_N + k4);
    *(float4*)&Bs[row][k4] = *(const float4*)(Wdt + (size_t)(n0 + row) * DT_RANK_ + k4);
  }
  __syncthreads();

  float acc[4][4] = {{0.f, 0.f, 0.f, 0.f}, {0.f, 0.f, 0.f, 0.f},
                     {0.f, 0.f, 0.f, 0.f}, {0.f, 0.f, 0.f, 0.f}};
  for (int kk = 0; kk < 64; kk += 4) {
    float4 a[4], b[4];
#pragma unroll
    for (int i = 0; i < 4; ++i) a[i] = *(const float4*)&As[tr * 4 + i][kk];
#pragma unroll
    for (int j = 0; j < 4; ++j) b[j] = *(const float4*)&Bs[tc * 4 + j][kk];
#pragma unroll
    for (int i = 0; i < 4; ++i)
#pragma unroll
      for (int j = 0; j < 4; ++j)
        acc[i][j] += a[i].x * b[j].x + a[i].y * b[j].y +
                     a[i].z * b[j].z + a[i].w * b[j].w;
  }
#pragma unroll
  for (int i = 0; i < 4; ++i) {
#pragma unroll
    for (int j = 0; j < 4; ++j) {
      float z = acc[i][j] + bdt[n0 + tc * 4 + j];
      float sp = fmaxf(z, 0.f) + log1pf(__expf(-fabsf(z)));   // stable softplus
      VIO<T>::st(dt + (size_t)(m0 + tr * 4 + i) * D_INNER_ + n0 + tc * 4 + j, sp);
    }
  }
}

// ---------------------------------------------------------------------------
// Register-state chunked scan, templated chunk count NCC (TCP = SEQ/NCC).
// Thread per (b, chunk, d), h[16] in VGPRs, manual 1-deep load prefetch.
// ---------------------------------------------------------------------------
template <int NCC, typename TD, typename TX>
__global__ __launch_bounds__(256) void scan2_reduce(
    const float* __restrict__ proj, const TD* __restrict__ dt,
    const TX* __restrict__ xs, const float* __restrict__ A_log,
    float* __restrict__ q, float* __restrict__ sdt)
{
  constexpr int TCP = SEQ / NCC;
  __shared__ float Bsh[TCP][16];
  const int tid = threadIdx.x;
  const int b = blockIdx.x / (NCC * 8);
  const int rem = blockIdx.x % (NCC * 8);
  const int c = rem >> 3;
  const int d = ((rem & 7) << 8) + tid;
  const size_t tok0 = (size_t)b * SEQ + (size_t)c * TCP;
  for (int sidx = tid; sidx < TCP * 4; sidx += 256) {   // stage B rows
    const int e = sidx * 4, t = e >> 4, col = e & 15;
    *(float4*)&Bsh[t][col] = *(const float4*)&proj[(tok0 + t) * XPROJ_N + DT_RANK_ + col];
  }
  float An[D_STATE_];
#pragma unroll
  for (int n = 0; n < D_STATE_; ++n) An[n] = -__expf(A_log[d * D_STATE_ + n]);
  __syncthreads();

  float h[D_STATE_];
#pragma unroll
  for (int n = 0; n < D_STATE_; ++n) h[n] = 0.f;
  float s = 0.f;
  float dtv = VIO<TD>::ld(&dt[tok0 * D_INNER_ + d]);
  float xsv = VIO<TX>::ld(&xs[tok0 * D_INNER_ + d]);
  for (int t = 0; t < TCP; ++t) {
    float dtn = 0.f, xsn = 0.f;
    if (t + 1 < TCP) {                          // prefetch next step
      dtn = VIO<TD>::ld(&dt[(tok0 + t + 1) * D_INNER_ + d]);
      xsn = VIO<TX>::ld(&xs[(tok0 + t + 1) * D_INNER_ + d]);
    }
    s += dtv;
    const float dx = dtv * xsv;
    float Bv[D_STATE_];
#pragma unroll
    for (int k = 0; k < 4; ++k)
      *(float4*)&Bv[4 * k] = *(const float4*)&Bsh[t][4 * k];
#pragma unroll
    for (int n = 0; n < D_STATE_; ++n)
      h[n] = __expf(dtv * An[n]) * h[n] + dx * Bv[n];
    dtv = dtn; xsv = xsn;
  }
  const size_t idx = (size_t)(b * NCC + c) * D_INNER_ + d;
#pragma unroll
  for (int k = 0; k < 4; ++k)
    *(float4*)&q[idx * D_STATE_ + 4 * k] =
        make_float4(h[4 * k], h[4 * k + 1], h[4 * k + 2], h[4 * k + 3]);
  sdt[idx] = s;
}

template <int NCC>
__global__ __launch_bounds__(256) void scan2_mid(
    float* __restrict__ q, const float* __restrict__ sdt,
    const float* __restrict__ A_log)
{
  const int gid = blockIdx.x * 256 + threadIdx.x;   // (b*D_INNER+d)*16+n
  const int n = gid & 15;
  const int d = (gid >> 4) & (D_INNER_ - 1);
  const int b = gid >> 15;
  const float An = -__expf(A_log[d * D_STATE_ + n]);
  float h = 0.f;
#pragma unroll
  for (int c = 0; c < NCC; ++c) {
    const size_t idx = (size_t)(b * NCC + c) * D_INNER_ + d;
    const float P = __expf(An * sdt[idx]);
    const float qq = q[idx * D_STATE_ + n];
    q[idx * D_STATE_ + n] = h;        // h at chunk start
    h = P * h + qq;
  }
}

template <int NCC, typename TD, typename TX>
__global__ __launch_bounds__(256) void scan2_apply(
    const float* __restrict__ proj, const TD* __restrict__ dt,
    const TX* __restrict__ xs, unsigned short* __restrict__ zy,
    const float* __restrict__ A_log, const float* __restrict__ D_par,
    const float* __restrict__ hstart)
{
  constexpr int TCP = SEQ / NCC;
  __shared__ float BC[TCP][32];     // [t][0..15] = B, [t][16..31] = C
  const int tid = threadIdx.x;
  const int b = blockIdx.x / (NCC * 8);
  const int rem = blockIdx.x % (NCC * 8);
  const int c = rem >> 3;
  const int d = ((rem & 7) << 8) + tid;
  const size_t tok0 = (size_t)b * SEQ + (size_t)c * TCP;
  for (int sidx = tid; sidx < TCP * 8; sidx += 256) {   // stage B+C
    const int e = sidx * 4, t = e >> 5, col = e & 31;
    *(float4*)&BC[t][col] = *(const float4*)&proj[(tok0 + t) * XPROJ_N + DT_RANK_ + col];
  }
  float An[D_STATE_];
#pragma unroll
  for (int n = 0; n < D_STATE_; ++n) An[n] = -__expf(A_log[d * D_STATE_ + n]);
  const float Dd = D_par[d];
  const size_t idx = (size_t)(b * NCC + c) * D_INNER_ + d;
  float h[D_STATE_];
#pragma unroll
  for (int k = 0; k < 4; ++k) {
    float4 v = *(const float4*)&hstart[idx * D_STATE_ + 4 * k];
    h[4 * k] = v.x; h[4 * k + 1] = v.y; h[4 * k + 2] = v.z; h[4 * k + 3] = v.w;
  }
  __syncthreads();

  float dtv = VIO<TD>::ld(&dt[tok0 * D_INNER_ + d]);
  float xsv = VIO<TX>::ld(&xs[tok0 * D_INNER_ + d]);
  float zv  = bf2f(zy[tok0 * D_INNER_ + d]);
  for (int t = 0; t < TCP; ++t) {
    float dtn = 0.f, xsn = 0.f, zn = 0.f;
    if (t + 1 < TCP) {                          // prefetch next step
      const size_t tt1 = (tok0 + t + 1) * D_INNER_ + d;
      dtn = VIO<TD>::ld(&dt[tt1]);
      xsn = VIO<TX>::ld(&xs[tt1]);
      zn  = bf2f(zy[tt1]);
    }
    const float dx = dtv * xsv;
    float Bv[D_STATE_], Cv[D_STATE_];
#pragma unroll
    for (int k = 0; k < 4; ++k) {
      *(float4*)&Bv[4 * k] = *(const float4*)&BC[t][4 * k];
      *(float4*)&Cv[4 * k] = *(const float4*)&BC[t][16 + 4 * k];
    }
    float y = 0.f;
#pragma unroll
    for (int n = 0; n < D_STATE_; ++n) {
      h[n] = __expf(dtv * An[n]) * h[n] + dx * Bv[n];
      y += h[n] * Cv[n];
    }
    const float g = zv / (1.f + __expf(-zv));      // silu(z)
    zy[(tok0 + t) * D_INNER_ + d] = f2bf((y + Dd * xsv) * g);
    dtv = dtn; xsv = xsn; zv = zn;
  }
}

// ---------------------------------------------------------------------------
// TD = dt storage, TX = xs storage, NCC = scan chunks.  qbuf/sdt = scratch.
template <int NCC, typename TD, typename TX>
static void run_pipeline(const float* x, const float* W_in, const float* W_conv,
                         const float* b_conv, const float* W_xp, const float* W_dt,
                         const float* b_dt, const float* A_log, const float* D_par,
                         const float* W_out, float* out,
                         unsigned short* xc, unsigned short* z, TX* xs,
                         TD* dtb, float* proj, float* qbuf, float* sdt,
                         hipStream_t stream)
{
  unsigned short* zy = z;   // scan overwrites z with gated y in place
  float* partial = out;                          // step 3 scratch (6.3 MiB)
  unsigned short* xbf   = (unsigned short*)xs;   // 4 MiB (xs written later)
  unsigned short* winbf = (unsigned short*)out;  // 8 MiB exactly
  unsigned short* wobf  = (unsigned short*)xs;   // 4 MiB (xs dead post-scan)

  // 0) pre-convert x and W_in to bf16
  f32_to_bf16<<<dim3(NTOK * D_MODEL / 2048), dim3(256), 0, stream>>>(
      x, xbf, NTOK * D_MODEL);
  f32_to_bf16<<<dim3(2 * D_INNER_ * D_MODEL / 2048), dim3(256), 0, stream>>>(
      W_in, winbf, 2 * D_INNER_ * D_MODEL);
  // 1) fused in-proj: [xc | z] = xbf @ winbf^T   (N=4096, split epilogue)
  gemm_bf16_nt<128, 128, 32, true, unsigned short>
      <<<dim3((NTOK / 128) * (2 * D_INNER_ / 128)), dim3(256), 0, stream>>>(
      xbf, winbf, xc, z, NTOK, 2 * D_INNER_, D_MODEL, D_INNER_);
  // 2) xs = silu(causal_dwconv(xc) + b_conv)
  conv_silu<unsigned short, TX><<<dim3(NTOK * D_INNER_ / 256), dim3(256), 0, stream>>>(
      xc, W_conv, b_conv, xs);
  // 3) proj = xs @ W_xproj^T   (split-K x8 into d_out, then reduce)
  gemm_proj_splitk<TX><<<dim3(SPLITK * (NTOK / 16)), dim3(256), 0, stream>>>(
      xs, W_xp, partial);
  proj_reduce<<<dim3(NTOK * XPROJ_N / 256), dim3(256), 0, stream>>>(partial, proj);
  // 4) dt = softplus(dt_low @ W_dt^T + b_dt)
  gemm_dt_softplus<TD><<<dim3((NTOK / 64) * (D_INNER_ / 64)), dim3(256), 0, stream>>>(
      proj, W_dt, b_dt, dtb);
  // 5) register-state chunked scan + gating  (z -> y*silu(z) in place)
  scan2_reduce<NCC, TD, TX><<<dim3(2 * NCC * 8), dim3(256), 0, stream>>>(
      proj, dtb, xs, A_log, qbuf, sdt);
  scan2_mid<NCC><<<dim3(2 * D_INNER_ * D_STATE_ / 256), dim3(256), 0, stream>>>(
      qbuf, sdt, A_log);
  scan2_apply<NCC, TD, TX><<<dim3(2 * NCC * 8), dim3(256), 0, stream>>>(
      proj, dtb, xs, zy, A_log, D_par, qbuf);
  // 5.5) convert W_out -> bf16 (xs region is dead now)
  f32_to_bf16<<<dim3(D_MODEL * D_INNER_ / 2048), dim3(256), 0, stream>>>(
      W_out, wobf, D_MODEL * D_INNER_);
  // 6) out = zy @ wobf^T
  gemm_bf16_nt<64, 64, 64, false, float>
      <<<dim3((NTOK / 64) * (D_MODEL / 64)), dim3(256), 0, stream>>>(
      zy, wobf, out, nullptr, NTOK, D_MODEL, D_INNER_, D_MODEL);
}

extern "C" void kernel_launch(void* const* d_in, const int* in_sizes, int n_in,
                              void* d_out, int out_size, void* d_ws, size_t ws_size,
                              hipStream_t stream)
{
  const float* x      = (const float*)d_in[0];
  const float* W_in   = (const float*)d_in[1];
  const float* W_conv = (const float*)d_in[2];
  const float* b_conv = (const float*)d_in[3];
  const float* W_xp   = (const float*)d_in[4];
  const float* W_dt   = (const float*)d_in[5];
  const float* b_dt   = (const float*)d_in[6];
  const float* A_log  = (const float*)d_in[7];
  const float* D_par  = (const float*)d_in[8];
  const float* W_out  = (const float*)d_in[9];
  float* out = (float*)d_out;

  const size_t NE = (size_t)NTOK * D_INNER_;          // 4,194,304 elements
  // tier1: xc(bf16) z(bf16) xs(f32) dt(f32) proj(f32) = 48.75 MiB
  const size_t need_t1 = NE * 2 + NE * 2 + NE * 4 + NE * 4
                       + (size_t)NTOK * XPROJ_N * 4;

  if (ws_size >= need_t1) {
    unsigned short* xc = (unsigned short*)d_ws;
    unsigned short* z  = xc + NE;
    float* xs   = (float*)(z + NE);
    float* dtb  = xs + NE;
    float* proj = dtb + NE;
    // NCC=32 scan scratch: q = 2*32*2048*16 f32 = 8 MiB -> d_out (exactly);
    // sdt = 512 KiB -> dead xc region (xc consumed by conv before scan).
    float* qbuf = out;
    float* sdt  = (float*)xc;
    run_pipeline<32, float, float>(x, W_in, W_conv, b_conv, W_xp, W_dt, b_dt,
                                   A_log, D_par, W_out, out, xc, z, xs, dtb,
                                   proj, qbuf, sdt, stream);
  } else {
    // tier2 (24.75 MiB): all bf16, dt aliases xc (xc dead after conv_silu);
    // NCC=16 scan scratch fits in d_out: q 4 MiB + sdt 256 KiB.
    unsigned short* xc = (unsigned short*)d_ws;
    unsigned short* z  = xc + NE;
    unsigned short* xs = z + NE;
    float* proj = (float*)(xs + NE);
    float* qbuf = out;
    float* sdt  = out + (size_t)2 * 16 * D_INNER_ * D_STATE_;
    run_pipeline<16, unsigned short, unsigned short>(
        x, W_in, W_conv, b_conv, W_xp, W_dt, b_dt, A_log,
        D_par, W_out, out, xc, z, xs, /*dtb=*/xc, proj, qbuf, sdt, stream);
  }
}

// Round 10
// 169.818 us; speedup vs baseline: 8.1737x; 1.1389x over previous
//
#include <hip/hip_runtime.h>
#include <math.h>

#define D_MODEL   1024
#define D_INNER_  2048
#define D_STATE_  16
#define DT_RANK_  64
#define SEQ       1024
#define NTOK      2048          // B * L
#define XPROJ_N   96            // dt_rank + 2*d_state

typedef __attribute__((ext_vector_type(8))) short s16x8;
typedef __attribute__((ext_vector_type(4))) float f32x4;

// ---------------- bf16 helpers ---------------------------------------------
__device__ __forceinline__ float bf2f(unsigned short u) {
  return __uint_as_float(((unsigned int)u) << 16);
}
__device__ __forceinline__ unsigned short f2bf(float f) {
  unsigned int x = __float_as_uint(f);
  x += 0x7FFF + ((x >> 16) & 1);          // round-to-nearest-even
  return (unsigned short)(x >> 16);
}

template <typename T> struct VIO;
template <> struct VIO<float> {
  static __device__ __forceinline__ float4 ld4(const float* p) { return *(const float4*)p; }
  static __device__ __forceinline__ float ld(const float* p) { return *p; }
  static __device__ __forceinline__ void st(float* p, float v) { *p = v; }
};
template <> struct VIO<unsigned short> {
  static __device__ __forceinline__ float4 ld4(const unsigned short* p) {
    ushort4 u = *(const ushort4*)p;
    return make_float4(bf2f(u.x), bf2f(u.y), bf2f(u.z), bf2f(u.w));
  }
  static __device__ __forceinline__ float ld(const unsigned short* p) { return bf2f(*p); }
  static __device__ __forceinline__ void st(unsigned short* p, float v) { *p = f2bf(v); }
};

// ---------------------------------------------------------------------------
// fp32 -> bf16 bulk convert (8 elems/thread).  n % 8 == 0.
// ---------------------------------------------------------------------------
__global__ __launch_bounds__(256) void f32_to_bf16(
    const float* __restrict__ s, unsigned short* __restrict__ d, int n)
{
  const int i = (blockIdx.x * 256 + threadIdx.x) * 8;
  if (i >= n) return;
  float4 a = *(const float4*)(s + i);
  float4 b = *(const float4*)(s + i + 4);
  s16x8 v;
  v[0] = (short)f2bf(a.x); v[1] = (short)f2bf(a.y);
  v[2] = (short)f2bf(a.z); v[3] = (short)f2bf(a.w);
  v[4] = (short)f2bf(b.x); v[5] = (short)f2bf(b.y);
  v[6] = (short)f2bf(b.z); v[7] = (short)f2bf(b.w);
  *(s16x8*)(d + i) = v;
}

// ---------------------------------------------------------------------------
// bf16 MFMA NT GEMM, templated tile.  (unchanged from round 8)
// ---------------------------------------------------------------------------
template <int BM, int BN, int BK, bool SPLIT, typename TCout>
__global__ __launch_bounds__(256) void gemm_bf16_nt(
    const unsigned short* __restrict__ A, const unsigned short* __restrict__ B,
    TCout* __restrict__ C0, TCout* __restrict__ C1,
    int M, int N, int K, int ldc)
{
  static_assert(BM * BK == 4096 && BN * BK == 4096, "staging map");
  constexpr int PITCH = BK + 8;                  // shorts; +16B pad
  constexpr int FI = BM / 32, FJ = BN / 32;      // frags per wave
  constexpr int TPR = BK / 16;                   // staging threads per row
  __shared__ __align__(16) short As[BM * PITCH];
  __shared__ __align__(16) short Bs[BN * PITCH];

  const int ntiles = N / BN;
  const int mt = blockIdx.x / ntiles, nt = blockIdx.x % ntiles;
  const int m0 = mt * BM, n0 = nt * BN;
  const int tid = threadIdx.x;
  const int lane = tid & 63;
  const int w = tid >> 6;
  const int wm = (w >> 1) * (BM / 2), wn = (w & 1) * (BN / 2);
  const int lrow = lane & 15;
  const int lk8 = (lane >> 4) << 3;

  const int arow = tid / TPR;                    // 0..BM-1
  const int koff = (tid % TPR) * 16;
  const unsigned short* pa = A + (size_t)(m0 + arow) * K + koff;
  const unsigned short* pb = B + (size_t)(n0 + arow) * K + koff;

  f32x4 acc[FI][FJ];
#pragma unroll
  for (int i = 0; i < FI; ++i)
#pragma unroll
    for (int j = 0; j < FJ; ++j) acc[i][j] = (f32x4){0.f, 0.f, 0.f, 0.f};

  s16x8 ra0 = *(const s16x8*)pa, ra1 = *(const s16x8*)(pa + 8);
  s16x8 rb0 = *(const s16x8*)pb, rb1 = *(const s16x8*)(pb + 8);

  for (int k0 = 0; k0 < K; k0 += BK) {
    __syncthreads();                             // previous compute done
    *(s16x8*)&As[arow * PITCH + koff]     = ra0;
    *(s16x8*)&As[arow * PITCH + koff + 8] = ra1;
    *(s16x8*)&Bs[arow * PITCH + koff]     = rb0;
    *(s16x8*)&Bs[arow * PITCH + koff + 8] = rb1;
    __syncthreads();
    if (k0 + BK < K) {                           // prefetch next tile (flies
      pa += BK; pb += BK;                        //  under the MFMA phase)
      ra0 = *(const s16x8*)pa; ra1 = *(const s16x8*)(pa + 8);
      rb0 = *(const s16x8*)pb; rb1 = *(const s16x8*)(pb + 8);
    }
    s16x8 af[FI][BK / 32], bfr[FJ][BK / 32];
#pragma unroll
    for (int ks = 0; ks < BK / 32; ++ks) {
#pragma unroll
      for (int i = 0; i < FI; ++i)
        af[i][ks] = *(const s16x8*)&As[(wm + i * 16 + lrow) * PITCH + ks * 32 + lk8];
#pragma unroll
      for (int j = 0; j < FJ; ++j)
        bfr[j][ks] = *(const s16x8*)&Bs[(wn + j * 16 + lrow) * PITCH + ks * 32 + lk8];
    }
#pragma unroll
    for (int ks = 0; ks < BK / 32; ++ks)
#pragma unroll
      for (int i = 0; i < FI; ++i)
#pragma unroll
        for (int j = 0; j < FJ; ++j)
          acc[i][j] = __builtin_amdgcn_mfma_f32_16x16x32_bf16(
              af[i][ks], bfr[j][ks], acc[i][j], 0, 0, 0);
  }

  // epilogue: C/D layout col = lane&15 (B idx), row = (lane>>4)*4+reg (A idx)
  const int crow0 = m0 + wm + (lane >> 4) * 4;
  TCout* dst = C0;
  int ccol0 = n0 + wn + lrow;
  if (SPLIT && n0 >= ldc) { dst = C1; ccol0 -= ldc; }
#pragma unroll
  for (int i = 0; i < FI; ++i)
#pragma unroll
    for (int j = 0; j < FJ; ++j)
#pragma unroll
      for (int r = 0; r < 4; ++r)
        VIO<TCout>::st(&dst[(size_t)(crow0 + i * 16 + r) * ldc + ccol0 + j * 16],
                       acc[i][j][r]);
}

// ---------------------------------------------------------------------------
// Causal depthwise conv (k=4, left pad 3) + bias + silu.
// DUAL: additionally store a bf16 copy (for the MFMA proj GEMM).
// ---------------------------------------------------------------------------
template <typename TIn, typename TOut, bool DUAL>
__global__ __launch_bounds__(256) void conv_silu(
    const TIn* __restrict__ xc, const float* __restrict__ Wc,
    const float* __restrict__ bc, TOut* __restrict__ xs,
    unsigned short* __restrict__ xs2)
{
  const int idx = blockIdx.x * 256 + threadIdx.x;   // NTOK * D_INNER
  const int d = idx & (D_INNER_ - 1);
  const int t = idx >> 11;                          // token = b*L + l
  const int l = t & (SEQ - 1);
  const float4 w = *(const float4*)(Wc + d * 4);    // W_conv[d][0][0..3]
  const TIn* col = xc + (size_t)t * D_INNER_ + d;
  float acc = bc[d] + VIO<TIn>::ld(col) * w.w;
  if (l >= 1) acc += VIO<TIn>::ld(col - D_INNER_)     * w.z;
  if (l >= 2) acc += VIO<TIn>::ld(col - 2 * D_INNER_) * w.y;
  if (l >= 3) acc += VIO<TIn>::ld(col - 3 * D_INNER_) * w.x;
  const float v = acc / (1.f + __expf(-acc));       // silu
  VIO<TOut>::st(&xs[idx], v);
  if (DUAL) xs2[idx] = f2bf(v);
}

// ---------------------------------------------------------------------------
// x-projection via MFMA, split-K: partial[s][m][e], SPK splits.
// BM=64 tokens x BN=96 (full N) per block, 4 waves 2x2 (32x48/wave, FI=2 FJ=3),
// BK=32, KCHUNK = 2048/SPK.  Grid = SPK * 32 blocks.
// ---------------------------------------------------------------------------
template <int SPK>
__global__ __launch_bounds__(256) void gemm_proj_mfma(
    const unsigned short* __restrict__ xsbf, const unsigned short* __restrict__ wxbf,
    float* __restrict__ partial)
{
  constexpr int BK = 32, KC = D_INNER_ / SPK;
  constexpr int PITCH = 40;
  __shared__ __align__(16) short As[64 * PITCH];
  __shared__ __align__(16) short Bs[96 * PITCH];
  const int mt = blockIdx.x & 31;            // 2048/64 m-tiles
  const int s  = blockIdx.x >> 5;            // K-split
  const int m0 = mt << 6;
  const int kbase = s * KC;
  const int tid = threadIdx.x, lane = tid & 63, w = tid >> 6;
  const int wm = (w >> 1) * 32, wn = (w & 1) * 48;
  const int lrow = lane & 15, lk8 = (lane >> 4) << 3;

  f32x4 acc[2][3];
#pragma unroll
  for (int i = 0; i < 2; ++i)
#pragma unroll
    for (int j = 0; j < 3; ++j) acc[i][j] = (f32x4){0.f, 0.f, 0.f, 0.f};

  for (int k0 = kbase; k0 < kbase + KC; k0 += BK) {
    __syncthreads();                         // previous compute done
    { // stage A: 64 x 32 (one s16x8 per thread)
      const int row = tid >> 2, ko = (tid & 3) << 3;
      *(s16x8*)&As[row * PITCH + ko] =
          *(const s16x8*)&xsbf[(size_t)(m0 + row) * D_INNER_ + k0 + ko];
    }
    // stage B: 96 x 32 (1.5 s16x8 per thread)
    for (int sidx = tid; sidx < 384; sidx += 256) {
      const int row = sidx >> 2, ko = (sidx & 3) << 3;
      *(s16x8*)&Bs[row * PITCH + ko] =
          *(const s16x8*)&wxbf[(size_t)row * D_INNER_ + k0 + ko];
    }
    __syncthreads();
    s16x8 af[2], bfr[3];
#pragma unroll
    for (int i = 0; i < 2; ++i)
      af[i] = *(const s16x8*)&As[(wm + i * 16 + lrow) * PITCH + lk8];
#pragma unroll
    for (int j = 0; j < 3; ++j)
      bfr[j] = *(const s16x8*)&Bs[(wn + j * 16 + lrow) * PITCH + lk8];
#pragma unroll
    for (int i = 0; i < 2; ++i)
#pragma unroll
      for (int j = 0; j < 3; ++j)
        acc[i][j] = __builtin_amdgcn_mfma_f32_16x16x32_bf16(
            af[i], bfr[j], acc[i][j], 0, 0, 0);
  }

  const int r0 = m0 + wm + (lane >> 4) * 4;
  const int c0 = wn + lrow;
#pragma unroll
  for (int i = 0; i < 2; ++i)
#pragma unroll
    for (int j = 0; j < 3; ++j)
#pragma unroll
      for (int r = 0; r < 4; ++r)
        partial[((size_t)s * NTOK + r0 + i * 16 + r) * XPROJ_N + c0 + j * 16] =
            acc[i][j][r];
}

template <int SPK>
__global__ __launch_bounds__(256) void proj_reduce(
    const float* __restrict__ partial, float* __restrict__ proj)
{
  const int gid = blockIdx.x * 256 + threadIdx.x;   // NTOK*XPROJ_N = 196608
  float s = 0.f;
#pragma unroll
  for (int i = 0; i < SPK; ++i)
    s += partial[(size_t)i * NTOK * XPROJ_N + gid];
  proj[gid] = s;
}

// ---------------------------------------------------------------------------
// dt GEMM (K=64) + bias + stable softplus.  (unchanged)
// ---------------------------------------------------------------------------
template <typename T>
__global__ __launch_bounds__(256) void gemm_dt_softplus(
    const float* __restrict__ proj, const float* __restrict__ Wdt,
    const float* __restrict__ bdt, T* __restrict__ dt)
{
  __shared__ float As[64][68];
  __shared__ float Bs[64][68];
  const int ntb = blockIdx.x & 31;          // D_INNER/64 = 32
  const int mt = blockIdx.x >> 5;
  const int m0 = mt << 6, n0 = ntb << 6;
  const int tid = threadIdx.x;
  const int tr = tid >> 4, tc = tid & 15;

#pragma unroll
  for (int q = 0; q < 4; ++q) {
    int f = tid + 256 * q;                  // f4 index into 64x64 tile
    int row = f >> 4, k4 = (f & 15) * 4;
    *(float4*)&As[row][k4] = *(const float4*)(proj + (size_t)(m0 + row) * XPROJ_N + k4);
    *(float4*)&Bs[row][k4] = *(const float4*)(Wdt + (size_t)(n0 + row) * DT_RANK_ + k4);
  }
  __syncthreads();

  float acc[4][4] = {{0.f, 0.f, 0.f, 0.f}, {0.f, 0.f, 0.f, 0.f},
                     {0.f, 0.f, 0.f, 0.f}, {0.f, 0.f, 0.f, 0.f}};
  for (int kk = 0; kk < 64; kk += 4) {
    float4 a[4], b[4];
#pragma unroll
    for (int i = 0; i < 4; ++i) a[i] = *(const float4*)&As[tr * 4 + i][kk];
#pragma unroll
    for (int j = 0; j < 4; ++j) b[j] = *(const float4*)&Bs[tc * 4 + j][kk];
#pragma unroll
    for (int i = 0; i < 4; ++i)
#pragma unroll
      for (int j = 0; j < 4; ++j)
        acc[i][j] += a[i].x * b[j].x + a[i].y * b[j].y +
                     a[i].z * b[j].z + a[i].w * b[j].w;
  }
#pragma unroll
  for (int i = 0; i < 4; ++i) {
#pragma unroll
    for (int j = 0; j < 4; ++j) {
      float z = acc[i][j] + bdt[n0 + tc * 4 + j];
      float sp = fmaxf(z, 0.f) + log1pf(__expf(-fabsf(z)));   // stable softplus
      VIO<T>::st(dt + (size_t)(m0 + tr * 4 + i) * D_INNER_ + n0 + tc * 4 + j, sp);
    }
  }
}

// ---------------------------------------------------------------------------
// Register-state chunked scan, templated chunk count NCC.  (unchanged)
// ---------------------------------------------------------------------------
template <int NCC, typename TD, typename TX>
__global__ __launch_bounds__(256) void scan2_reduce(
    const float* __restrict__ proj, const TD* __restrict__ dt,
    const TX* __restrict__ xs, const float* __restrict__ A_log,
    float* __restrict__ q, float* __restrict__ sdt)
{
  constexpr int TCP = SEQ / NCC;
  __shared__ float Bsh[TCP][16];
  const int tid = threadIdx.x;
  const int b = blockIdx.x / (NCC * 8);
  const int rem = blockIdx.x % (NCC * 8);
  const int c = rem >> 3;
  const int d = ((rem & 7) << 8) + tid;
  const size_t tok0 = (size_t)b * SEQ + (size_t)c * TCP;
  for (int sidx = tid; sidx < TCP * 4; sidx += 256) {   // stage B rows
    const int e = sidx * 4, t = e >> 4, col = e & 15;
    *(float4*)&Bsh[t][col] = *(const float4*)&proj[(tok0 + t) * XPROJ_N + DT_RANK_ + col];
  }
  float An[D_STATE_];
#pragma unroll
  for (int n = 0; n < D_STATE_; ++n) An[n] = -__expf(A_log[d * D_STATE_ + n]);
  __syncthreads();

  float h[D_STATE_];
#pragma unroll
  for (int n = 0; n < D_STATE_; ++n) h[n] = 0.f;
  float s = 0.f;
  float dtv = VIO<TD>::ld(&dt[tok0 * D_INNER_ + d]);
  float xsv = VIO<TX>::ld(&xs[tok0 * D_INNER_ + d]);
  for (int t = 0; t < TCP; ++t) {
    float dtn = 0.f, xsn = 0.f;
    if (t + 1 < TCP) {                          // prefetch next step
      dtn = VIO<TD>::ld(&dt[(tok0 + t + 1) * D_INNER_ + d]);
      xsn = VIO<TX>::ld(&xs[(tok0 + t + 1) * D_INNER_ + d]);
    }
    s += dtv;
    const float dx = dtv * xsv;
    float Bv[D_STATE_];
#pragma unroll
    for (int k = 0; k < 4; ++k)
      *(float4*)&Bv[4 * k] = *(const float4*)&Bsh[t][4 * k];
#pragma unroll
    for (int n = 0; n < D_STATE_; ++n)
      h[n] = __expf(dtv * An[n]) * h[n] + dx * Bv[n];
    dtv = dtn; xsv = xsn;
  }
  const size_t idx = (size_t)(b * NCC + c) * D_INNER_ + d;
#pragma unroll
  for (int k = 0; k < 4; ++k)
    *(float4*)&q[idx * D_STATE_ + 4 * k] =
        make_float4(h[4 * k], h[4 * k + 1], h[4 * k + 2], h[4 * k + 3]);
  sdt[idx] = s;
}

template <int NCC>
__global__ __launch_bounds__(256) void scan2_mid(
    float* __restrict__ q, const float* __restrict__ sdt,
    const float* __restrict__ A_log)
{
  const int gid = blockIdx.x * 256 + threadIdx.x;   // (b*D_INNER+d)*16+n
  const int n = gid & 15;
  const int d = (gid >> 4) & (D_INNER_ - 1);
  const int b = gid >> 15;
  const float An = -__expf(A_log[d * D_STATE_ + n]);
  float h = 0.f;
#pragma unroll
  for (int c = 0; c < NCC; ++c) {
    const size_t idx = (size_t)(b * NCC + c) * D_INNER_ + d;
    const float P = __expf(An * sdt[idx]);
    const float qq = q[idx * D_STATE_ + n];
    q[idx * D_STATE_ + n] = h;        // h at chunk start
    h = P * h + qq;
  }
}

template <int NCC, typename TD, typename TX>
__global__ __launch_bounds__(256) void scan2_apply(
    const float* __restrict__ proj, const TD* __restrict__ dt,
    const TX* __restrict__ xs, unsigned short* __restrict__ zy,
    const float* __restrict__ A_log, const float* __restrict__ D_par,
    const float* __restrict__ hstart)
{
  constexpr int TCP = SEQ / NCC;
  __shared__ float BC[TCP][32];     // [t][0..15] = B, [t][16..31] = C
  const int tid = threadIdx.x;
  const int b = blockIdx.x / (NCC * 8);
  const int rem = blockIdx.x % (NCC * 8);
  const int c = rem >> 3;
  const int d = ((rem & 7) << 8) + tid;
  const size_t tok0 = (size_t)b * SEQ + (size_t)c * TCP;
  for (int sidx = tid; sidx < TCP * 8; sidx += 256) {   // stage B+C
    const int e = sidx * 4, t = e >> 5, col = e & 31;
    *(float4*)&BC[t][col] = *(const float4*)&proj[(tok0 + t) * XPROJ_N + DT_RANK_ + col];
  }
  float An[D_STATE_];
#pragma unroll
  for (int n = 0; n < D_STATE_; ++n) An[n] = -__expf(A_log[d * D_STATE_ + n]);
  const float Dd = D_par[d];
  const size_t idx = (size_t)(b * NCC + c) * D_INNER_ + d;
  float h[D_STATE_];
#pragma unroll
  for (int k = 0; k < 4; ++k) {
    float4 v = *(const float4*)&hstart[idx * D_STATE_ + 4 * k];
    h[4 * k] = v.x; h[4 * k + 1] = v.y; h[4 * k + 2] = v.z; h[4 * k + 3] = v.w;
  }
  __syncthreads();

  float dtv = VIO<TD>::ld(&dt[tok0 * D_INNER_ + d]);
  float xsv = VIO<TX>::ld(&xs[tok0 * D_INNER_ + d]);
  float zv  = bf2f(zy[tok0 * D_INNER_ + d]);
  for (int t = 0; t < TCP; ++t) {
    float dtn = 0.f, xsn = 0.f, zn = 0.f;
    if (t + 1 < TCP) {                          // prefetch next step
      const size_t tt1 = (tok0 + t + 1) * D_INNER_ + d;
      dtn = VIO<TD>::ld(&dt[tt1]);
      xsn = VIO<TX>::ld(&xs[tt1]);
      zn  = bf2f(zy[tt1]);
    }
    const float dx = dtv * xsv;
    float Bv[D_STATE_], Cv[D_STATE_];
#pragma unroll
    for (int k = 0; k < 4; ++k) {
      *(float4*)&Bv[4 * k] = *(const float4*)&BC[t][4 * k];
      *(float4*)&Cv[4 * k] = *(const float4*)&BC[t][16 + 4 * k];
    }
    float y = 0.f;
#pragma unroll
    for (int n = 0; n < D_STATE_; ++n) {
      h[n] = __expf(dtv * An[n]) * h[n] + dx * Bv[n];
      y += h[n] * Cv[n];
    }
    const float g = zv / (1.f + __expf(-zv));      // silu(z)
    zy[(tok0 + t) * D_INNER_ + d] = f2bf((y + Dd * xsv) * g);
    dtv = dtn; xsv = xsn; zv = zn;
  }
}

// ---------------------------------------------------------------------------
// NCC = scan chunks, SPK = proj K-splits, DUALCONV = conv writes bf16 copy.
// xsbf: bf16 xs for proj MFMA (== xs in tier2).  wxbf aliases proj buffer
// (dead once proj_reduce writes).  partial aliases dt buffer (dead until
// gemm_dt_softplus writes it, which happens after proj_reduce).
template <int NCC, int SPK, bool DUALCONV, typename TD, typename TX>
static void run_pipeline(const float* x, const float* W_in, const float* W_conv,
                         const float* b_conv, const float* W_xp, const float* W_dt,
                         const float* b_dt, const float* A_log, const float* D_par,
                         const float* W_out, float* out,
                         unsigned short* xc, unsigned short* z, TX* xs,
                         unsigned short* xsbf, TD* dtb, float* partial,
                         float* proj, float* qbuf, float* sdt,
                         hipStream_t stream)
{
  unsigned short* zy = z;   // scan overwrites z with gated y in place
  unsigned short* xbf   = (unsigned short*)xs;   // x bf16 (xs written later)
  unsigned short* winbf = (unsigned short*)out;  // 8 MiB exactly, dead post-step1
  unsigned short* wxbf  = (unsigned short*)proj; // 384 KiB, dead post-reduce
  unsigned short* wobf  = (unsigned short*)xs;   // xs dead post-scan

  // 0) pre-convert x and W_in to bf16
  f32_to_bf16<<<dim3(NTOK * D_MODEL / 2048), dim3(256), 0, stream>>>(
      x, xbf, NTOK * D_MODEL);
  f32_to_bf16<<<dim3(2 * D_INNER_ * D_MODEL / 2048), dim3(256), 0, stream>>>(
      W_in, winbf, 2 * D_INNER_ * D_MODEL);
  // 1) fused in-proj: [xc | z] = xbf @ winbf^T   (N=4096, split epilogue)
  gemm_bf16_nt<128, 128, 32, true, unsigned short>
      <<<dim3((NTOK / 128) * (2 * D_INNER_ / 128)), dim3(256), 0, stream>>>(
      xbf, winbf, xc, z, NTOK, 2 * D_INNER_, D_MODEL, D_INNER_);
  // 2) xs = silu(causal_dwconv(xc) + b_conv)  (+ bf16 copy when DUALCONV)
  conv_silu<unsigned short, TX, DUALCONV>
      <<<dim3(NTOK * D_INNER_ / 256), dim3(256), 0, stream>>>(
      xc, W_conv, b_conv, xs, xsbf);
  // 2.5) convert W_xproj to bf16 (into proj buffer -- consumed before reduce)
  f32_to_bf16<<<dim3(XPROJ_N * D_INNER_ / 2048), dim3(256), 0, stream>>>(
      W_xp, wxbf, XPROJ_N * D_INNER_);
  // 3) proj = xs @ W_xproj^T   (MFMA split-K, partials in dt region)
  gemm_proj_mfma<SPK><<<dim3(SPK * 32), dim3(256), 0, stream>>>(
      xsbf, wxbf, partial);
  proj_reduce<SPK><<<dim3(NTOK * XPROJ_N / 256), dim3(256), 0, stream>>>(
      partial, proj);
  // 4) dt = softplus(dt_low @ W_dt^T + b_dt)   (overwrites partial region)
  gemm_dt_softplus<TD><<<dim3((NTOK / 64) * (D_INNER_ / 64)), dim3(256), 0, stream>>>(
      proj, W_dt, b_dt, dtb);
  // 5) register-state chunked scan + gating  (z -> y*silu(z) in place)
  scan2_reduce<NCC, TD, TX><<<dim3(2 * NCC * 8), dim3(256), 0, stream>>>(
      proj, dtb, xs, A_log, qbuf, sdt);
  scan2_mid<NCC><<<dim3(2 * D_INNER_ * D_STATE_ / 256), dim3(256), 0, stream>>>(
      qbuf, sdt, A_log);
  scan2_apply<NCC, TD, TX><<<dim3(2 * NCC * 8), dim3(256), 0, stream>>>(
      proj, dtb, xs, zy, A_log, D_par, qbuf);
  // 5.5) convert W_out -> bf16 (xs region is dead now)
  f32_to_bf16<<<dim3(D_MODEL * D_INNER_ / 2048), dim3(256), 0, stream>>>(
      W_out, wobf, D_MODEL * D_INNER_);
  // 6) out = zy @ wobf^T
  gemm_bf16_nt<64, 64, 64, false, float>
      <<<dim3((NTOK / 64) * (D_MODEL / 64)), dim3(256), 0, stream>>>(
      zy, wobf, out, nullptr, NTOK, D_MODEL, D_INNER_, D_MODEL);
}

extern "C" void kernel_launch(void* const* d_in, const int* in_sizes, int n_in,
                              void* d_out, int out_size, void* d_ws, size_t ws_size,
                              hipStream_t stream)
{
  const float* x      = (const float*)d_in[0];
  const float* W_in   = (const float*)d_in[1];
  const float* W_conv = (const float*)d_in[2];
  const float* b_conv = (const float*)d_in[3];
  const float* W_xp   = (const float*)d_in[4];
  const float* W_dt   = (const float*)d_in[5];
  const float* b_dt   = (const float*)d_in[6];
  const float* A_log  = (const float*)d_in[7];
  const float* D_par  = (const float*)d_in[8];
  const float* W_out  = (const float*)d_in[9];
  float* out = (float*)d_out;

  const size_t NE = (size_t)NTOK * D_INNER_;          // 4,194,304 elements
  // tier1: xc(bf16) z(bf16) xs(f32) dt(f32) proj(f32) = 48.75 MiB
  const size_t need_t1 = NE * 2 + NE * 2 + NE * 4 + NE * 4
                       + (size_t)NTOK * XPROJ_N * 4;

  if (ws_size >= need_t1) {
    unsigned short* xc = (unsigned short*)d_ws;
    unsigned short* z  = xc + NE;
    float* xs   = (float*)(z + NE);
    float* dtb  = xs + NE;
    float* proj = dtb + NE;
    // xsbf (bf16 copy of xs, 8 MiB) lives in d_out between step 2 and the
    // scan's qbuf; partial (SPK*2048*96 f32 = 12.6 MiB) aliases dtb (16 MiB);
    // sdt (512 KiB) aliases dead xc; qbuf = d_out (8 MiB, post-proj).
    unsigned short* xsbf = (unsigned short*)out;
    float* partial = dtb;
    float* qbuf = out;
    float* sdt  = (float*)xc;
    run_pipeline<32, 16, true, float, float>(
        x, W_in, W_conv, b_conv, W_xp, W_dt, b_dt, A_log, D_par, W_out, out,
        xc, z, xs, xsbf, dtb, partial, proj, qbuf, sdt, stream);
  } else {
    // tier2 (24.75 MiB): all bf16; xs already bf16 -> xsbf = xs (no dual);
    // dt aliases xc; partial (SPK=8 -> 6.3 MiB) aliases xc region too
    // (f32 view, 8 MiB — dt written after reduce); scan scratch in d_out.
    unsigned short* xc = (unsigned short*)d_ws;
    unsigned short* z  = xc + NE;
    unsigned short* xs = z + NE;
    float* proj = (float*)(xs + NE);
    float* partial = (float*)xc;
    float* qbuf = out;
    float* sdt  = out + (size_t)2 * 16 * D_INNER_ * D_STATE_;
    run_pipeline<16, 8, false, unsigned short, unsigned short>(
        x, W_in, W_conv, b_conv, W_xp, W_dt, b_dt, A_log, D_par, W_out, out,
        xc, z, xs, /*xsbf=*/xs, /*dtb=*/xc, partial, proj, qbuf, sdt, stream);
  }
}